// Round 4
// baseline (849.780 us; speedup 1.0000x reference)
//
#include <hip/hip_runtime.h>
#include <hip/hip_bf16.h>
#include <stdint.h>

// GraRPINet: 2-layer GAT. N=40000 nodes, E=640000 edges.
// R3: all GEMMs -> bf16 MFMA (16x16x32), weights pre-transposed to bf16 BT[n][k],
// h0/h1/z1/z2 stored bf16. No atomics (R2 lesson: atomic split-K = 164MB writes @680GB/s).
// R4 (reverted): LDS-free embed regressed (179us) -- scattered per-lane loads, no pipelining.
// R5 (neutral): 1-deep register prefetch: compiler drains vmcnt(0) at every s_barrier.
// R6 (reverted): split-K via fp32 partials regressed (191us): +178MB DRAM traffic and
// L3 pollution killed x-residency (FETCH 115->171MB, WRITE 10->127MB). Lesson: never
// add DRAM-visible intermediates on this problem.
// R7: embed concurrency with ZERO extra traffic: BM 64->32, 128-thread blocks (2 waves).
// Grid (2,1250)=2500 blocks (~10/CU vs 2.4/CU): independent barrier groups overlap the
// per-barrier vmcnt drains. LDS 13.8KB, traffic identical to R5.

#define HEADS 4
#define CH1   64
#define CH2   32
#define HC1   256
#define HC2   128

static constexpr int D_RNA  = 1000;
static constexpr int D_PROT = 300;
static constexpr int D_IN   = 1300;
static constexpr int HDIM   = 128;  // 2H

typedef __bf16 bf16x8 __attribute__((ext_vector_type(8)));
typedef float  f32x4  __attribute__((ext_vector_type(4)));
typedef unsigned short ushort;

__device__ __forceinline__ float lrelu(float x) { return x >= 0.f ? x : 0.2f * x; }
__device__ __forceinline__ float bf2f(unsigned int u16) {
  return __uint_as_float(u16 << 16);
}
__device__ __forceinline__ ushort f2bf(float f) {
  union { float f; unsigned int u; } x; x.f = f;
  unsigned int r = x.u + 0x7fffu + ((x.u >> 16) & 1u);
  return (ushort)(r >> 16);
}

// ---------------- small utility kernels ----------------
__global__ void zero_i32(int* p, int n) {
  int i = blockIdx.x * 256 + threadIdx.x;
  if (i < n) p[i] = 0;
}

__global__ void hist_kernel(const int* __restrict__ dstv, int* __restrict__ deg, int E) {
  int i = blockIdx.x * 256 + threadIdx.x;
  if (i < E) atomicAdd(&deg[dstv[i]], 1);
}

__global__ void scan_kernel(const int* __restrict__ deg, int* __restrict__ off,
                            int* __restrict__ cur, int n) {
  __shared__ int s[1024];
  int tid = threadIdx.x;
  const int CHK = (n + 1023) / 1024;
  int base = tid * CHK;
  int sum = 0;
  for (int j = 0; j < CHK; ++j) {
    int i = base + j;
    if (i < n) sum += deg[i];
  }
  s[tid] = sum;
  __syncthreads();
  for (int o = 1; o < 1024; o <<= 1) {
    int t = (tid >= o) ? s[tid - o] : 0;
    __syncthreads();
    s[tid] += t;
    __syncthreads();
  }
  int run = s[tid] - sum;
  for (int j = 0; j < CHK; ++j) {
    int i = base + j;
    if (i < n) {
      off[i] = run; cur[i] = run;
      run += deg[i];
    }
  }
  if (tid == 1023) off[n] = s[1023];
}

__global__ void scatter_kernel(const int* __restrict__ srcv, const int* __restrict__ dstv,
                               int* __restrict__ cur, int* __restrict__ srcs, int E) {
  int i = blockIdx.x * 256 + threadIdx.x;
  if (i < E) {
    int d = dstv[i];
    int pos = atomicAdd(&cur[d], 1);
    srcs[pos] = srcv[i];
  }
}

// fold att vectors: v[k,h] = sum_c W[k, h*CH+c] * att[h,c]
__global__ void fold_att_kernel(const float* __restrict__ W1s, const float* __restrict__ W1d,
                                const float* __restrict__ at1s, const float* __restrict__ at1d,
                                const float* __restrict__ W2s, const float* __restrict__ W2d,
                                const float* __restrict__ at2s, const float* __restrict__ at2d,
                                float* v1s, float* v1d, float* v2s, float* v2d) {
  int tid = blockIdx.x * blockDim.x + threadIdx.x;
  int stride = gridDim.x * blockDim.x;
  for (int o = tid; o < HDIM * HEADS; o += stride) {
    int k = o >> 2, h = o & 3;
    float ss = 0.f, sd = 0.f;
    for (int c = 0; c < CH1; ++c) {
      ss += W1s[k * HC1 + h * CH1 + c] * at1s[h * CH1 + c];
      sd += W1d[k * HC1 + h * CH1 + c] * at1d[h * CH1 + c];
    }
    v1s[o] = ss; v1d[o] = sd;
  }
  for (int o = tid; o < HC1 * HEADS; o += stride) {
    int k = o >> 2, h = o & 3;
    float ss = 0.f, sd = 0.f;
    for (int c = 0; c < CH2; ++c) {
      ss += W2s[k * HC2 + h * CH2 + c] * at2s[h * CH2 + c];
      sd += W2d[k * HC2 + h * CH2 + c] * at2d[h * CH2 + c];
    }
    v2s[o] = ss; v2d[o] = sd;
  }
}

// ---------------- weight preprocessing: transpose + bf16 ----------------
// BTr[64][1024] (k>=1000 zero), BTp[64][320] (k>=300 zero),
// BT1[512][128] = [W1s|Wl1]^T, BT2[256][256] = [W2s|Wl2]^T, concat biases.
__global__ void convert_weights(const float* __restrict__ W_rna, const float* __restrict__ W_prot,
                                const float* __restrict__ W1s, const float* __restrict__ Wl1,
                                const float* __restrict__ W2s, const float* __restrict__ Wl2,
                                const float* __restrict__ b1, const float* __restrict__ bl1,
                                const float* __restrict__ b2, const float* __restrict__ bl2,
                                ushort* BTr, ushort* BTp, ushort* BT1, ushort* BT2,
                                float* biasL1, float* biasL2) {
  int tid = blockIdx.x * blockDim.x + threadIdx.x;
  int stride = gridDim.x * blockDim.x;
  for (int i = tid; i < 64 * 1024; i += stride) {
    int n = i >> 10, k = i & 1023;
    BTr[i] = (k < D_RNA) ? f2bf(W_rna[k * 64 + n]) : 0;
  }
  for (int i = tid; i < 64 * 320; i += stride) {
    int n = i / 320, k = i - n * 320;
    BTp[i] = (k < D_PROT) ? f2bf(W_prot[k * 64 + n]) : 0;
  }
  for (int i = tid; i < 512 * 128; i += stride) {
    int n = i >> 7, k = i & 127;
    BT1[i] = f2bf(n < 256 ? W1s[k * 256 + n] : Wl1[k * 256 + n - 256]);
  }
  for (int i = tid; i < 256 * 256; i += stride) {
    int n = i >> 8, k = i & 255;
    BT2[i] = f2bf(n < 128 ? W2s[k * 128 + n] : Wl2[k * 128 + n - 128]);
  }
  for (int i = tid; i < 512; i += stride) biasL1[i] = (i < 256) ? b1[i] : bl1[i - 256];
  for (int i = tid; i < 256; i += stride) biasL2[i] = (i < 128) ? b2[i] : bl2[i - 128];
}

#define LDK 72  // padded k-stride (shorts) for 64-wide k tiles: 144B rows -> 2-way-only conflicts

__device__ __forceinline__ f32x4 mfma_bf16(bf16x8 a, bf16x8 b, f32x4 c) {
  return __builtin_amdgcn_mfma_f32_16x16x32_bf16(a, b, c, 0, 0, 0);
}

// ---------------- embedding MFMA GEMM: h0[N,128] bf16 ----------------
// grid (2, N/32): x=0 rna (K=1024 padded), x=1 prot (K=320 padded). 128 threads,
// BM=32 (2 waves): 2500 blocks (~10/CU) so many independent barrier groups overlap
// their vmcnt drains. Traffic identical to the BM=64 version (rows are disjoint).
__launch_bounds__(128)
__global__ void embed_gemm(const float* __restrict__ x,
                           const ushort* __restrict__ BTr, const ushort* __restrict__ BTp,
                           const float* __restrict__ b_rna, const float* __restrict__ b_prot,
                           ushort* __restrict__ h0) {
  const bool prot = (blockIdx.x == 1);
  const int Kpad = prot ? 320 : 1024;
  const int acol = prot ? D_RNA : 0;
  const ushort* BT = prot ? BTp : BTr;
  const float* bias = prot ? b_prot : b_rna;
  const int r0 = blockIdx.y * 32;

  __shared__ ushort As[32 * LDK];
  __shared__ ushort Bs[64 * LDK];
  int tid = threadIdx.x;            // 0..127
  int wave = tid >> 6, lane = tid & 63;
  int quad = lane >> 4, lr = lane & 15;
  f32x4 acc[4];
#pragma unroll
  for (int c = 0; c < 4; ++c) acc[c] = (f32x4){0.f, 0.f, 0.f, 0.f};

  // A staging: 32 rows x 64 k, 16 k per thread. B staging: 64 cols x 64 k, 32 k/thread.
  int sarow = tid >> 2, sakq = (tid & 3) * 16;
  int sbrow = tid >> 1, sbkq = (tid & 1) * 32;
  const float* aprow = x + (size_t)(r0 + sarow) * D_IN + acol;
  const ushort* bprow = BT + (size_t)sbrow * Kpad;

  float4 fa[4];
  uint4 fb[4];
  auto loadA = [&](int k0) {
#pragma unroll
    for (int q = 0; q < 4; ++q) {
      int kg = acol + k0 + sakq + q * 4;
      fa[q] = (kg + 4 <= D_IN) ? *(const float4*)(aprow + k0 + sakq + q * 4)
                               : make_float4(0.f, 0.f, 0.f, 0.f);
    }
  };
  auto loadB = [&](int k0) {
    const ushort* bp = bprow + k0 + sbkq;
#pragma unroll
    for (int q = 0; q < 4; ++q) fb[q] = *(const uint4*)(bp + q * 8);
  };

  loadA(0);
  loadB(0);

  for (int k0 = 0; k0 < Kpad; k0 += 64) {
    // stage prefetched registers -> LDS (A converts fp32->bf16)
    {
      ushort tmp[16];
#pragma unroll
      for (int q = 0; q < 4; ++q) {
        tmp[q * 4 + 0] = f2bf(fa[q].x); tmp[q * 4 + 1] = f2bf(fa[q].y);
        tmp[q * 4 + 2] = f2bf(fa[q].z); tmp[q * 4 + 3] = f2bf(fa[q].w);
      }
      *(uint4*)&As[sarow * LDK + sakq] = *(const uint4*)&tmp[0];
      *(uint4*)&As[sarow * LDK + sakq + 8] = *(const uint4*)&tmp[8];
#pragma unroll
      for (int q = 0; q < 4; ++q)
        *(uint4*)&Bs[sbrow * LDK + sbkq + q * 8] = fb[q];
    }
    __syncthreads();
    // issue next tile's global loads NOW; consumed after next barrier
    if (k0 + 64 < Kpad) {
      loadA(k0 + 64);
      loadB(k0 + 64);
    }
    int arow = wave * 16 + lr;
    bf16x8 a0 = *(const bf16x8*)&As[arow * LDK + quad * 8];
    bf16x8 a1 = *(const bf16x8*)&As[arow * LDK + 32 + quad * 8];
#pragma unroll
    for (int c = 0; c < 4; ++c) {
      bf16x8 b0 = *(const bf16x8*)&Bs[(c * 16 + lr) * LDK + quad * 8];
      bf16x8 b1 = *(const bf16x8*)&Bs[(c * 16 + lr) * LDK + 32 + quad * 8];
      acc[c] = mfma_bf16(a0, b0, acc[c]);
      acc[c] = mfma_bf16(a1, b1, acc[c]);
    }
    __syncthreads();
  }
  int colb = prot ? 64 : 0;
#pragma unroll
  for (int c = 0; c < 4; ++c) {
#pragma unroll
    for (int j = 0; j < 4; ++j) {
      int row = r0 + wave * 16 + quad * 4 + j;
      int col = c * 16 + lr;
      h0[(size_t)row * HDIM + colb + col] = f2bf(acc[c][j] + bias[col]);
    }
  }
}

// ---------------- layer MFMA GEMM: [out0|out1][N, halfw each] bf16 = A[N,K]bf16 @ BT^T --------
// grid (OUTW/64, N/64). K = 128 or 256 (multiple of 64). 1-deep prefetch (R5).
__launch_bounds__(256)
__global__ void layer_gemm(const ushort* __restrict__ A, int K,
                           const ushort* __restrict__ BT, const float* __restrict__ bias,
                           ushort* __restrict__ out0, ushort* __restrict__ out1, int halfw) {
  const int cb = blockIdx.x * 64;
  const int r0 = blockIdx.y * 64;
  __shared__ ushort As[64 * LDK];
  __shared__ ushort Bs[64 * LDK];
  int tid = threadIdx.x;
  int wave = tid >> 6, lane = tid & 63;
  int quad = lane >> 4, lr = lane & 15;
  f32x4 acc[4];
#pragma unroll
  for (int c = 0; c < 4; ++c) acc[c] = (f32x4){0.f, 0.f, 0.f, 0.f};

  int srow = tid >> 2, skq = (tid & 3) * 16;
  const ushort* aprow = A + (size_t)(r0 + srow) * K;
  const ushort* bprow = BT + (size_t)(cb + srow) * K;

  uint4 fa0, fa1, fb0, fb1;
  auto loadAB = [&](int k0) {
    const ushort* ap = aprow + k0 + skq;
    const ushort* bp = bprow + k0 + skq;
    fa0 = *(const uint4*)ap;
    fa1 = *(const uint4*)(ap + 8);
    fb0 = *(const uint4*)bp;
    fb1 = *(const uint4*)(bp + 8);
  };

  loadAB(0);

  for (int k0 = 0; k0 < K; k0 += 64) {
    *(uint4*)&As[srow * LDK + skq] = fa0;
    *(uint4*)&As[srow * LDK + skq + 8] = fa1;
    *(uint4*)&Bs[srow * LDK + skq] = fb0;
    *(uint4*)&Bs[srow * LDK + skq + 8] = fb1;
    __syncthreads();
    if (k0 + 64 < K) loadAB(k0 + 64);
    int arow = wave * 16 + lr;
    bf16x8 a0 = *(const bf16x8*)&As[arow * LDK + quad * 8];
    bf16x8 a1 = *(const bf16x8*)&As[arow * LDK + 32 + quad * 8];
#pragma unroll
    for (int c = 0; c < 4; ++c) {
      bf16x8 b0 = *(const bf16x8*)&Bs[(c * 16 + lr) * LDK + quad * 8];
      bf16x8 b1 = *(const bf16x8*)&Bs[(c * 16 + lr) * LDK + 32 + quad * 8];
      acc[c] = mfma_bf16(a0, b0, acc[c]);
      acc[c] = mfma_bf16(a1, b1, acc[c]);
    }
    __syncthreads();
  }
#pragma unroll
  for (int c = 0; c < 4; ++c) {
#pragma unroll
    for (int j = 0; j < 4; ++j) {
      int row = r0 + wave * 16 + quad * 4 + j;
      int cg = cb + c * 16 + lr;
      ushort v = f2bf(acc[c][j] + bias[cg]);
      if (cg < halfw) out0[(size_t)row * halfw + cg] = v;
      else            out1[(size_t)row * halfw + cg - halfw] = v;
    }
  }
}

// ---------------- attention logits: a_s/a_d[N,4] = h[N,K](bf16) @ v[K,4] ----------------
__launch_bounds__(256)
__global__ void attn_proj_kernel(const ushort* __restrict__ h, int K,
                                 const float* __restrict__ vs, const float* __restrict__ vd,
                                 float* __restrict__ a_s, float* __restrict__ a_d, int N) {
  extern __shared__ float lds[];
  float* VsT = lds;
  float* VdT = lds + 4 * K;
  for (int idx = threadIdx.x; idx < 4 * K; idx += 256) {
    int j = idx / K, k = idx - j * K;
    VsT[j * K + k] = vs[k * 4 + j];
    VdT[j * K + k] = vd[k * 4 + j];
  }
  __syncthreads();
  int wave = threadIdx.x >> 6, lane = threadIdx.x & 63;
  int n = blockIdx.x * 4 + wave;
  if (n >= N) return;
  float as[4] = {0.f, 0.f, 0.f, 0.f}, ad[4] = {0.f, 0.f, 0.f, 0.f};
  const ushort* hp = h + (size_t)n * K;
  for (int k = lane; k < K; k += 64) {
    float hv = bf2f(hp[k]);
#pragma unroll
    for (int j = 0; j < 4; ++j) {
      as[j] += hv * VsT[j * K + k];
      ad[j] += hv * VdT[j * K + k];
    }
  }
#pragma unroll
  for (int j = 0; j < 4; ++j) {
    for (int o = 32; o; o >>= 1) {
      as[j] += __shfl_xor(as[j], o);
      ad[j] += __shfl_xor(ad[j], o);
    }
  }
  if (lane == 0) {
#pragma unroll
    for (int j = 0; j < 4; ++j) {
      a_s[(size_t)n * 4 + j] = as[j];
      a_d[(size_t)n * 4 + j] = ad[j];
    }
  }
}

// -------- per-dst segment softmax: 16 lanes per node, 4 nodes/wave --------
__launch_bounds__(256)
__global__ void edge_softmax_kernel(const int* __restrict__ off, const int* __restrict__ srcs,
                                    const float* __restrict__ a_s, const float* __restrict__ a_d,
                                    float* __restrict__ alpha, float* __restrict__ rden, int N) {
  int lane = threadIdx.x & 63;
  int wave = threadIdx.x >> 6;
  int g = lane >> 4, l = lane & 15;
  int n = (blockIdx.x * 4 + wave) * 4 + g;
  if (n >= N) return;
  int s0 = off[n], s1 = off[n + 1];
  float4 ad = *(const float4*)&a_d[(size_t)n * 4];
  float mx = -1e30f, my = -1e30f, mz = -1e30f, mw = -1e30f;
  for (int i = s0 + l; i < s1; i += 16) {
    float4 as = *(const float4*)&a_s[(size_t)srcs[i] * 4];
    mx = fmaxf(mx, lrelu(as.x + ad.x));
    my = fmaxf(my, lrelu(as.y + ad.y));
    mz = fmaxf(mz, lrelu(as.z + ad.z));
    mw = fmaxf(mw, lrelu(as.w + ad.w));
  }
#pragma unroll
  for (int o = 1; o < 16; o <<= 1) {
    mx = fmaxf(mx, __shfl_xor(mx, o));
    my = fmaxf(my, __shfl_xor(my, o));
    mz = fmaxf(mz, __shfl_xor(mz, o));
    mw = fmaxf(mw, __shfl_xor(mw, o));
  }
  float sx = 0.f, sy = 0.f, sz = 0.f, sw = 0.f;
  for (int i = s0 + l; i < s1; i += 16) {
    float4 as = *(const float4*)&a_s[(size_t)srcs[i] * 4];
    float4 p;
    p.x = expf(lrelu(as.x + ad.x) - mx);
    p.y = expf(lrelu(as.y + ad.y) - my);
    p.z = expf(lrelu(as.z + ad.z) - mz);
    p.w = expf(lrelu(as.w + ad.w) - mw);
    sx += p.x; sy += p.y; sz += p.z; sw += p.w;
    *(float4*)&alpha[(size_t)i * 4] = p;
  }
#pragma unroll
  for (int o = 1; o < 16; o <<= 1) {
    sx += __shfl_xor(sx, o);
    sy += __shfl_xor(sy, o);
    sz += __shfl_xor(sz, o);
    sw += __shfl_xor(sw, o);
  }
  if (l == 0) {
    float4 r;
    r.x = sx > 0.f ? 1.f / sx : 0.f;
    r.y = sy > 0.f ? 1.f / sy : 0.f;
    r.z = sz > 0.f ? 1.f / sz : 0.f;
    r.w = sw > 0.f ? 1.f / sw : 0.f;
    *(float4*)&rden[(size_t)n * 4] = r;
  }
}

// ---------------- weighted aggregate + bias + skip(bf16) (+relu) ----------------
template <int VEC>
__device__ __forceinline__ void load_bf(const ushort* p, float* out);
template <>
__device__ __forceinline__ void load_bf<4>(const ushort* p, float* out) {
  uint2 q = *(const uint2*)p;
  out[0] = bf2f(q.x & 0xffffu); out[1] = bf2f(q.x >> 16);
  out[2] = bf2f(q.y & 0xffffu); out[3] = bf2f(q.y >> 16);
}
template <>
__device__ __forceinline__ void load_bf<2>(const ushort* p, float* out) {
  unsigned int q = *(const unsigned int*)p;
  out[0] = bf2f(q & 0xffffu); out[1] = bf2f(q >> 16);
}

template <int CH, int VEC, bool RELU, bool OUT_BF16>
__launch_bounds__(256)
__global__ void aggregate_kernel(const int* __restrict__ off, const int* __restrict__ srcs,
                                 const float* __restrict__ alpha, const float* __restrict__ rden,
                                 const ushort* __restrict__ xs,
                                 const float* __restrict__ bias,
                                 const ushort* __restrict__ skip,
                                 void* __restrict__ outv, int N) {
  const int HC = 4 * CH;
  int wave = threadIdx.x >> 6, lane = threadIdx.x & 63;
  int n = blockIdx.x * 4 + wave;
  if (n >= N) return;
  int h = lane >> 4;
  int c = (lane & 15) * VEC;
  int i = off[n], end = off[n + 1];
  float acc[VEC];
#pragma unroll
  for (int v = 0; v < VEC; ++v) acc[v] = 0.f;
  for (; i + 2 <= end; i += 2) {
    int sA = srcs[i], sB = srcs[i + 1];
    float wA = alpha[(size_t)i * 4 + h];
    float wB = alpha[(size_t)(i + 1) * 4 + h];
    float xA[VEC], xB[VEC];
    load_bf<VEC>(xs + (size_t)sA * HC + h * CH + c, xA);
    load_bf<VEC>(xs + (size_t)sB * HC + h * CH + c, xB);
#pragma unroll
    for (int v = 0; v < VEC; ++v) acc[v] += wA * xA[v] + wB * xB[v];
  }
  if (i < end) {
    int sA = srcs[i];
    float wA = alpha[(size_t)i * 4 + h];
    float xA[VEC];
    load_bf<VEC>(xs + (size_t)sA * HC + h * CH + c, xA);
#pragma unroll
    for (int v = 0; v < VEC; ++v) acc[v] += wA * xA[v];
  }
  float r = rden[(size_t)n * 4 + h];
  size_t obase = (size_t)n * HC + h * CH + c;
  float sk[VEC];
  load_bf<VEC>(skip + obase, sk);
#pragma unroll
  for (int v = 0; v < VEC; ++v) {
    float val = acc[v] * r + bias[h * CH + c + v] + sk[v];
    if (RELU) val = fmaxf(val, 0.f);
    if (OUT_BF16) ((ushort*)outv)[obase + v] = f2bf(val);
    else          ((float*)outv)[obase + v] = val;
  }
}

// ---------------- host launch ----------------
extern "C" void kernel_launch(void* const* d_in, const int* in_sizes, int n_in,
                              void* d_out, int out_size, void* d_ws, size_t ws_size,
                              hipStream_t stream) {
  const float* x      = (const float*)d_in[0];
  const int*   ei     = (const int*)d_in[1];
  const float* W_rna  = (const float*)d_in[3];
  const float* b_rna  = (const float*)d_in[4];
  const float* W_prot = (const float*)d_in[5];
  const float* b_prot = (const float*)d_in[6];
  const float* W1s    = (const float*)d_in[7];
  const float* W1d    = (const float*)d_in[8];
  const float* at1s   = (const float*)d_in[9];
  const float* at1d   = (const float*)d_in[10];
  const float* bias1  = (const float*)d_in[11];
  const float* Wl1    = (const float*)d_in[12];
  const float* bl1    = (const float*)d_in[13];
  const float* W2s    = (const float*)d_in[14];
  const float* W2d    = (const float*)d_in[15];
  const float* at2s   = (const float*)d_in[16];
  const float* at2d   = (const float*)d_in[17];
  const float* bias2  = (const float*)d_in[18];
  const float* Wl2    = (const float*)d_in[19];
  const float* bl2    = (const float*)d_in[20];

  const int N = in_sizes[0] / D_IN;   // 40000
  const int E = in_sizes[1] / 2;      // 640000
  const int* srcv = ei;
  const int* dstv = ei + E;

  char* ws = (char*)d_ws;
  size_t o = 0;
  auto carve = [&](size_t bytes) {
    void* p = ws + o;
    o += (bytes + 255) & ~(size_t)255;
    return p;
  };
  int* deg    = (int*)carve((size_t)N * 4);
  int* offp   = (int*)carve((size_t)(N + 1) * 4);
  int* cur    = (int*)carve((size_t)N * 4);
  int* srcs   = (int*)carve((size_t)E * 4);
  float* v1s  = (float*)carve(HDIM * HEADS * 4);
  float* v1d  = (float*)carve(HDIM * HEADS * 4);
  float* v2s  = (float*)carve(HC1 * HEADS * 4);
  float* v2d  = (float*)carve(HC1 * HEADS * 4);
  float* a_s  = (float*)carve((size_t)N * 4 * 4);
  float* a_d  = (float*)carve((size_t)N * 4 * 4);
  float* rden = (float*)carve((size_t)N * 4 * 4);
  float* alpha = (float*)carve((size_t)E * 4 * 4);
  ushort* BTr = (ushort*)carve(64 * 1024 * 2);
  ushort* BTp = (ushort*)carve(64 * 320 * 2);
  ushort* BT1 = (ushort*)carve(512 * 128 * 2);
  ushort* BT2 = (ushort*)carve(256 * 256 * 2);
  float* biasL1 = (float*)carve(512 * 4);
  float* biasL2 = (float*)carve(256 * 4);
  ushort* h0  = (ushort*)carve((size_t)N * HDIM * 2);
  ushort* xs1 = (ushort*)carve((size_t)N * HC1 * 2);
  ushort* z1  = (ushort*)carve((size_t)N * HC1 * 2);
  ushort* h1  = (ushort*)carve((size_t)N * HC1 * 2);
  ushort* xs2 = h0;   // h0 dead after layer-1 gemm + attn_proj1
  ushort* z2  = z1;   // z1 dead after aggregate1
  float* out = (float*)d_out;

  // 1. counting-sort edges by dst
  zero_i32<<<(N + 255) / 256, 256, 0, stream>>>(deg, N);
  hist_kernel<<<(E + 255) / 256, 256, 0, stream>>>(dstv, deg, E);
  scan_kernel<<<1, 1024, 0, stream>>>(deg, offp, cur, N);
  scatter_kernel<<<(E + 255) / 256, 256, 0, stream>>>(srcv, dstv, cur, srcs, E);
  // 2. fold att + weight conversion
  fold_att_kernel<<<8, 256, 0, stream>>>(W1s, W1d, at1s, at1d, W2s, W2d, at2s, at2d,
                                         v1s, v1d, v2s, v2d);
  convert_weights<<<256, 256, 0, stream>>>(W_rna, W_prot, W1s, Wl1, W2s, Wl2,
                                           bias1, bl1, bias2, bl2,
                                           BTr, BTp, BT1, BT2, biasL1, biasL2);
  // 3. embedding -> h0[N,128] bf16 (BM=32, 2500 blocks)
  embed_gemm<<<dim3(2, N / 32), 128, 0, stream>>>(x, BTr, BTp, b_rna, b_prot, h0);
  // 4. layer-1: [xs1|z1] = h0 @ [W1s|Wl1] (+bias), bf16
  layer_gemm<<<dim3(8, N / 64), 256, 0, stream>>>(h0, HDIM, BT1, biasL1, xs1, z1, HC1);
  attn_proj_kernel<<<N / 4, 256, 8 * HDIM * 4, stream>>>(h0, HDIM, v1s, v1d, a_s, a_d, N);
  // 5. layer-1 softmax + aggregate -> h1 = relu(agg + bias1 + z1), bf16
  edge_softmax_kernel<<<N / 16, 256, 0, stream>>>(offp, srcs, a_s, a_d, alpha, rden, N);
  aggregate_kernel<CH1, 4, true, true><<<N / 4, 256, 0, stream>>>(offp, srcs, alpha, rden, xs1,
                                                                  bias1, z1, h1, N);
  // 6. layer-2
  layer_gemm<<<dim3(4, N / 64), 256, 0, stream>>>(h1, HC1, BT2, biasL2, xs2, z2, HC2);
  attn_proj_kernel<<<N / 4, 256, 8 * HC1 * 4, stream>>>(h1, HC1, v2s, v2d, a_s, a_d, N);
  edge_softmax_kernel<<<N / 16, 256, 0, stream>>>(offp, srcs, a_s, a_d, alpha, rden, N);
  aggregate_kernel<CH2, 2, false, false><<<N / 4, 256, 0, stream>>>(offp, srcs, alpha, rden, xs2,
                                                                    bias2, z2, out, N);
}

// Round 5
// 706.741 us; speedup vs baseline: 1.2024x; 1.2024x over previous
//
#include <hip/hip_runtime.h>
#include <hip/hip_bf16.h>
#include <stdint.h>

// GraRPINet: 2-layer GAT. N=40000 nodes, E=640000 edges.
// R3: all GEMMs -> bf16 MFMA (16x16x32), weights pre-transposed bf16 BT[n][k].
// R4/R6/R7 (reverted): LDS-free embed, split-K partials, BM=32 all regressed --
// embed's R5 config is a local optimum (123us); any schedule/traffic change broke
// L3 x-residency or L2 write-combining. Lesson: zero extra DRAM-visible traffic.
// R5: 1-deep register prefetch in GEMMs (neutral-to-slightly-positive). Best: 762us.
// R8: eliminate whole kernels with zero added traffic:
//  (a) attn_proj folded into layer_gemm as one extra column-block whose B is the
//      folded att vectors (bf16 hi+lo rows -> fp32-accurate logits, epilogue
//      shfl_xor(4) sums hi+lo, stores fp32 a_s/a_d).
//  (b) edge_softmax fused into aggregate (gat_fused_kernel): max pass + single
//      exp+sum+accumulate pass; alpha/rden buffers deleted.

#define HEADS 4
#define CH1   64
#define CH2   32
#define HC1   256
#define HC2   128

static constexpr int D_RNA  = 1000;
static constexpr int D_PROT = 300;
static constexpr int D_IN   = 1300;
static constexpr int HDIM   = 128;  // 2H

typedef __bf16 bf16x8 __attribute__((ext_vector_type(8)));
typedef float  f32x4  __attribute__((ext_vector_type(4)));
typedef unsigned short ushort;

__device__ __forceinline__ float lrelu(float x) { return x >= 0.f ? x : 0.2f * x; }
__device__ __forceinline__ float bf2f(unsigned int u16) {
  return __uint_as_float(u16 << 16);
}
__device__ __forceinline__ ushort f2bf(float f) {
  union { float f; unsigned int u; } x; x.f = f;
  unsigned int r = x.u + 0x7fffu + ((x.u >> 16) & 1u);
  return (ushort)(r >> 16);
}

// ---------------- small utility kernels ----------------
__global__ void zero_i32(int* p, int n) {
  int i = blockIdx.x * 256 + threadIdx.x;
  if (i < n) p[i] = 0;
}

__global__ void hist_kernel(const int* __restrict__ dstv, int* __restrict__ deg, int E) {
  int i = blockIdx.x * 256 + threadIdx.x;
  if (i < E) atomicAdd(&deg[dstv[i]], 1);
}

__global__ void scan_kernel(const int* __restrict__ deg, int* __restrict__ off,
                            int* __restrict__ cur, int n) {
  __shared__ int s[1024];
  int tid = threadIdx.x;
  const int CHK = (n + 1023) / 1024;
  int base = tid * CHK;
  int sum = 0;
  for (int j = 0; j < CHK; ++j) {
    int i = base + j;
    if (i < n) sum += deg[i];
  }
  s[tid] = sum;
  __syncthreads();
  for (int o = 1; o < 1024; o <<= 1) {
    int t = (tid >= o) ? s[tid - o] : 0;
    __syncthreads();
    s[tid] += t;
    __syncthreads();
  }
  int run = s[tid] - sum;
  for (int j = 0; j < CHK; ++j) {
    int i = base + j;
    if (i < n) {
      off[i] = run; cur[i] = run;
      run += deg[i];
    }
  }
  if (tid == 1023) off[n] = s[1023];
}

__global__ void scatter_kernel(const int* __restrict__ srcv, const int* __restrict__ dstv,
                               int* __restrict__ cur, int* __restrict__ srcs, int E) {
  int i = blockIdx.x * 256 + threadIdx.x;
  if (i < E) {
    int d = dstv[i];
    int pos = atomicAdd(&cur[d], 1);
    srcs[pos] = srcv[i];
  }
}

// fold att vectors v[k,h] = sum_c W[k, h*CH+c]*att[h,c], then pack as GEMM B-tiles:
// BTA[64][K]: rows 0..3 = vs_hi, 4..7 = vs_lo, 8..11 = vd_hi, 12..15 = vd_lo,
// rows 16..63 = 0. hi/lo bf16 split keeps logits at ~fp32 precision.
__global__ void fold_att_kernel(const float* __restrict__ W1s, const float* __restrict__ W1d,
                                const float* __restrict__ at1s, const float* __restrict__ at1d,
                                const float* __restrict__ W2s, const float* __restrict__ W2d,
                                const float* __restrict__ at2s, const float* __restrict__ at2d,
                                ushort* __restrict__ BTA1, ushort* __restrict__ BTA2) {
  int tid = blockIdx.x * blockDim.x + threadIdx.x;
  int stride = gridDim.x * blockDim.x;
  for (int o = tid; o < HDIM * HEADS; o += stride) {
    int k = o >> 2, h = o & 3;
    float ss = 0.f, sd = 0.f;
    for (int c = 0; c < CH1; ++c) {
      ss += W1s[k * HC1 + h * CH1 + c] * at1s[h * CH1 + c];
      sd += W1d[k * HC1 + h * CH1 + c] * at1d[h * CH1 + c];
    }
    ushort sh = f2bf(ss), dh = f2bf(sd);
    BTA1[(0 + h) * HDIM + k] = sh;
    BTA1[(4 + h) * HDIM + k] = f2bf(ss - bf2f(sh));
    BTA1[(8 + h) * HDIM + k] = dh;
    BTA1[(12 + h) * HDIM + k] = f2bf(sd - bf2f(dh));
  }
  for (int o = tid; o < HC1 * HEADS; o += stride) {
    int k = o >> 2, h = o & 3;
    float ss = 0.f, sd = 0.f;
    for (int c = 0; c < CH2; ++c) {
      ss += W2s[k * HC2 + h * CH2 + c] * at2s[h * CH2 + c];
      sd += W2d[k * HC2 + h * CH2 + c] * at2d[h * CH2 + c];
    }
    ushort sh = f2bf(ss), dh = f2bf(sd);
    BTA2[(0 + h) * HC1 + k] = sh;
    BTA2[(4 + h) * HC1 + k] = f2bf(ss - bf2f(sh));
    BTA2[(8 + h) * HC1 + k] = dh;
    BTA2[(12 + h) * HC1 + k] = f2bf(sd - bf2f(dh));
  }
  for (int i = tid; i < 48 * HDIM; i += stride) BTA1[16 * HDIM + i] = 0;
  for (int i = tid; i < 48 * HC1; i += stride) BTA2[16 * HC1 + i] = 0;
}

// ---------------- weight preprocessing: transpose + bf16 ----------------
// BTr[64][1024] (k>=1000 zero), BTp[64][320] (k>=300 zero),
// BT1[512][128] = [W1s|Wl1]^T, BT2[256][256] = [W2s|Wl2]^T, concat biases.
__global__ void convert_weights(const float* __restrict__ W_rna, const float* __restrict__ W_prot,
                                const float* __restrict__ W1s, const float* __restrict__ Wl1,
                                const float* __restrict__ W2s, const float* __restrict__ Wl2,
                                const float* __restrict__ b1, const float* __restrict__ bl1,
                                const float* __restrict__ b2, const float* __restrict__ bl2,
                                ushort* BTr, ushort* BTp, ushort* BT1, ushort* BT2,
                                float* biasL1, float* biasL2) {
  int tid = blockIdx.x * blockDim.x + threadIdx.x;
  int stride = gridDim.x * blockDim.x;
  for (int i = tid; i < 64 * 1024; i += stride) {
    int n = i >> 10, k = i & 1023;
    BTr[i] = (k < D_RNA) ? f2bf(W_rna[k * 64 + n]) : 0;
  }
  for (int i = tid; i < 64 * 320; i += stride) {
    int n = i / 320, k = i - n * 320;
    BTp[i] = (k < D_PROT) ? f2bf(W_prot[k * 64 + n]) : 0;
  }
  for (int i = tid; i < 512 * 128; i += stride) {
    int n = i >> 7, k = i & 127;
    BT1[i] = f2bf(n < 256 ? W1s[k * 256 + n] : Wl1[k * 256 + n - 256]);
  }
  for (int i = tid; i < 256 * 256; i += stride) {
    int n = i >> 8, k = i & 255;
    BT2[i] = f2bf(n < 128 ? W2s[k * 128 + n] : Wl2[k * 128 + n - 128]);
  }
  for (int i = tid; i < 512; i += stride) biasL1[i] = (i < 256) ? b1[i] : bl1[i - 256];
  for (int i = tid; i < 256; i += stride) biasL2[i] = (i < 128) ? b2[i] : bl2[i - 128];
}

#define LDK 72  // padded k-stride (shorts) for 64-wide k tiles: 144B rows -> 2-way-only conflicts

__device__ __forceinline__ f32x4 mfma_bf16(bf16x8 a, bf16x8 b, f32x4 c) {
  return __builtin_amdgcn_mfma_f32_16x16x32_bf16(a, b, c, 0, 0, 0);
}

// ---------------- embedding MFMA GEMM: h0[N,128] bf16 (R5-exact, local optimum) -------
__launch_bounds__(256)
__global__ void embed_gemm(const float* __restrict__ x,
                           const ushort* __restrict__ BTr, const ushort* __restrict__ BTp,
                           const float* __restrict__ b_rna, const float* __restrict__ b_prot,
                           ushort* __restrict__ h0) {
  const bool prot = (blockIdx.x == 1);
  const int Kpad = prot ? 320 : 1024;
  const int acol = prot ? D_RNA : 0;
  const ushort* BT = prot ? BTp : BTr;
  const float* bias = prot ? b_prot : b_rna;
  const int r0 = blockIdx.y * 64;

  __shared__ ushort As[64 * LDK];
  __shared__ ushort Bs[64 * LDK];
  int tid = threadIdx.x;
  int wave = tid >> 6, lane = tid & 63;
  int quad = lane >> 4, lr = lane & 15;
  f32x4 acc[4];
#pragma unroll
  for (int c = 0; c < 4; ++c) acc[c] = (f32x4){0.f, 0.f, 0.f, 0.f};

  int srow = tid >> 2, skq = (tid & 3) * 16;
  const float* aprow = x + (size_t)(r0 + srow) * D_IN;
  const ushort* bprow = BT + (size_t)srow * Kpad;

  float4 fa[4];
  uint4 fb0, fb1;

  auto loadA = [&](int k0) {
#pragma unroll
    for (int q = 0; q < 4; ++q) {
      int kg = acol + k0 + skq + q * 4;
      fa[q] = (kg + 4 <= D_IN) ? *(const float4*)(aprow + kg)
                               : make_float4(0.f, 0.f, 0.f, 0.f);
    }
  };
  auto loadB = [&](int k0) {
    const ushort* bp = bprow + k0 + skq;
    fb0 = *(const uint4*)bp;
    fb1 = *(const uint4*)(bp + 8);
  };

  loadA(0);
  loadB(0);

  for (int k0 = 0; k0 < Kpad; k0 += 64) {
    {
      ushort tmp[16];
#pragma unroll
      for (int q = 0; q < 4; ++q) {
        tmp[q * 4 + 0] = f2bf(fa[q].x); tmp[q * 4 + 1] = f2bf(fa[q].y);
        tmp[q * 4 + 2] = f2bf(fa[q].z); tmp[q * 4 + 3] = f2bf(fa[q].w);
      }
      *(uint4*)&As[srow * LDK + skq] = *(const uint4*)&tmp[0];
      *(uint4*)&As[srow * LDK + skq + 8] = *(const uint4*)&tmp[8];
      *(uint4*)&Bs[srow * LDK + skq] = fb0;
      *(uint4*)&Bs[srow * LDK + skq + 8] = fb1;
    }
    __syncthreads();
    if (k0 + 64 < Kpad) {
      loadA(k0 + 64);
      loadB(k0 + 64);
    }
    int arow = wave * 16 + lr;
    bf16x8 a0 = *(const bf16x8*)&As[arow * LDK + quad * 8];
    bf16x8 a1 = *(const bf16x8*)&As[arow * LDK + 32 + quad * 8];
#pragma unroll
    for (int c = 0; c < 4; ++c) {
      bf16x8 b0 = *(const bf16x8*)&Bs[(c * 16 + lr) * LDK + quad * 8];
      bf16x8 b1 = *(const bf16x8*)&Bs[(c * 16 + lr) * LDK + 32 + quad * 8];
      acc[c] = mfma_bf16(a0, b0, acc[c]);
      acc[c] = mfma_bf16(a1, b1, acc[c]);
    }
    __syncthreads();
  }
  int colb = prot ? 64 : 0;
#pragma unroll
  for (int c = 0; c < 4; ++c) {
#pragma unroll
    for (int j = 0; j < 4; ++j) {
      int row = r0 + wave * 16 + quad * 4 + j;
      int col = c * 16 + lr;
      h0[(size_t)row * HDIM + colb + col] = f2bf(acc[c][j] + bias[col]);
    }
  }
}

// ---------------- layer MFMA GEMM + folded attention logits ----------------
// grid (OUTW/64 + 1, N/64). Last x-block uses BTA as B and writes fp32 a_s/a_d:
// out col t(0..3) hi + col t+4 lo summed via shfl_xor(4) -> a_s; cols 8..15 -> a_d.
__launch_bounds__(256)
__global__ void layer_gemm(const ushort* __restrict__ A, int K,
                           const ushort* __restrict__ BT, const float* __restrict__ bias,
                           ushort* __restrict__ out0, ushort* __restrict__ out1, int halfw,
                           const ushort* __restrict__ BTA,
                           float* __restrict__ a_s, float* __restrict__ a_d) {
  const bool att = (blockIdx.x == gridDim.x - 1);
  const int cb = att ? 0 : blockIdx.x * 64;
  const int r0 = blockIdx.y * 64;
  __shared__ ushort As[64 * LDK];
  __shared__ ushort Bs[64 * LDK];
  int tid = threadIdx.x;
  int wave = tid >> 6, lane = tid & 63;
  int quad = lane >> 4, lr = lane & 15;
  f32x4 acc[4];
#pragma unroll
  for (int c = 0; c < 4; ++c) acc[c] = (f32x4){0.f, 0.f, 0.f, 0.f};

  int srow = tid >> 2, skq = (tid & 3) * 16;
  const ushort* aprow = A + (size_t)(r0 + srow) * K;
  const ushort* bprow = att ? (BTA + (size_t)srow * K)
                            : (BT + (size_t)(cb + srow) * K);

  uint4 fa0, fa1, fb0, fb1;
  auto loadAB = [&](int k0) {
    const ushort* ap = aprow + k0 + skq;
    const ushort* bp = bprow + k0 + skq;
    fa0 = *(const uint4*)ap;
    fa1 = *(const uint4*)(ap + 8);
    fb0 = *(const uint4*)bp;
    fb1 = *(const uint4*)(bp + 8);
  };

  loadAB(0);

  for (int k0 = 0; k0 < K; k0 += 64) {
    *(uint4*)&As[srow * LDK + skq] = fa0;
    *(uint4*)&As[srow * LDK + skq + 8] = fa1;
    *(uint4*)&Bs[srow * LDK + skq] = fb0;
    *(uint4*)&Bs[srow * LDK + skq + 8] = fb1;
    __syncthreads();
    if (k0 + 64 < K) loadAB(k0 + 64);
    int arow = wave * 16 + lr;
    bf16x8 a0 = *(const bf16x8*)&As[arow * LDK + quad * 8];
    bf16x8 a1 = *(const bf16x8*)&As[arow * LDK + 32 + quad * 8];
#pragma unroll
    for (int c = 0; c < 4; ++c) {
      bf16x8 b0 = *(const bf16x8*)&Bs[(c * 16 + lr) * LDK + quad * 8];
      bf16x8 b1 = *(const bf16x8*)&Bs[(c * 16 + lr) * LDK + 32 + quad * 8];
      acc[c] = mfma_bf16(a0, b0, acc[c]);
      acc[c] = mfma_bf16(a1, b1, acc[c]);
    }
    __syncthreads();
  }
  if (att) {
#pragma unroll
    for (int j = 0; j < 4; ++j) {
      int row = r0 + wave * 16 + quad * 4 + j;
      float v0 = acc[0][j];
      float sum = v0 + __shfl_xor(v0, 4);   // hi + lo partner
      if (lr < 4)                    a_s[(size_t)row * 4 + lr] = sum;
      else if (lr >= 8 && lr < 12)   a_d[(size_t)row * 4 + (lr - 8)] = sum;
    }
    return;
  }
#pragma unroll
  for (int c = 0; c < 4; ++c) {
#pragma unroll
    for (int j = 0; j < 4; ++j) {
      int row = r0 + wave * 16 + quad * 4 + j;
      int cg = cb + c * 16 + lr;
      ushort v = f2bf(acc[c][j] + bias[cg]);
      if (cg < halfw) out0[(size_t)row * halfw + cg] = v;
      else            out1[(size_t)row * halfw + cg - halfw] = v;
    }
  }
}

// ---------------- fused segment softmax + weighted aggregate + bias + skip (+relu) ----
// One wave per node; lane = (head h, channel group c). Pass A: per-head max over
// incoming edges (gather a_s[src][h], broadcast across the 16 lanes of a head).
// Pass B: p = exp(e - m); s += p; acc += p * xs[src]. Epilogue: acc/s + bias + skip.
// Identical arithmetic to the former edge_softmax + aggregate pair; alpha/rden gone.
template <int VEC>
__device__ __forceinline__ void load_bf(const ushort* p, float* out);
template <>
__device__ __forceinline__ void load_bf<4>(const ushort* p, float* out) {
  uint2 q = *(const uint2*)p;
  out[0] = bf2f(q.x & 0xffffu); out[1] = bf2f(q.x >> 16);
  out[2] = bf2f(q.y & 0xffffu); out[3] = bf2f(q.y >> 16);
}
template <>
__device__ __forceinline__ void load_bf<2>(const ushort* p, float* out) {
  unsigned int q = *(const unsigned int*)p;
  out[0] = bf2f(q & 0xffffu); out[1] = bf2f(q >> 16);
}

template <int CH, int VEC, bool RELU, bool OUT_BF16>
__launch_bounds__(256)
__global__ void gat_fused_kernel(const int* __restrict__ off, const int* __restrict__ srcs,
                                 const float* __restrict__ a_s, const float* __restrict__ a_d,
                                 const ushort* __restrict__ xs,
                                 const float* __restrict__ bias,
                                 const ushort* __restrict__ skip,
                                 void* __restrict__ outv, int N) {
  const int HC = 4 * CH;
  int wave = threadIdx.x >> 6, lane = threadIdx.x & 63;
  int n = blockIdx.x * 4 + wave;
  if (n >= N) return;
  int h = lane >> 4;
  int c = (lane & 15) * VEC;
  int s0 = off[n], end = off[n + 1];
  float adn = a_d[(size_t)n * 4 + h];

  // pass A: max logit per head
  float m = -1e30f;
  int i = s0;
  for (; i + 4 <= end; i += 4) {
    float e0 = a_s[(size_t)srcs[i] * 4 + h];
    float e1 = a_s[(size_t)srcs[i + 1] * 4 + h];
    float e2 = a_s[(size_t)srcs[i + 2] * 4 + h];
    float e3 = a_s[(size_t)srcs[i + 3] * 4 + h];
    m = fmaxf(m, fmaxf(fmaxf(lrelu(e0 + adn), lrelu(e1 + adn)),
                       fmaxf(lrelu(e2 + adn), lrelu(e3 + adn))));
  }
  for (; i < end; ++i) m = fmaxf(m, lrelu(a_s[(size_t)srcs[i] * 4 + h] + adn));

  // pass B: exp + sum + weighted accumulate
  float s = 0.f;
  float acc[VEC];
#pragma unroll
  for (int v = 0; v < VEC; ++v) acc[v] = 0.f;
  for (i = s0; i + 2 <= end; i += 2) {
    int sA = srcs[i], sB = srcs[i + 1];
    float pA = __expf(lrelu(a_s[(size_t)sA * 4 + h] + adn) - m);
    float pB = __expf(lrelu(a_s[(size_t)sB * 4 + h] + adn) - m);
    s += pA + pB;
    float xA[VEC], xB[VEC];
    load_bf<VEC>(xs + (size_t)sA * HC + h * CH + c, xA);
    load_bf<VEC>(xs + (size_t)sB * HC + h * CH + c, xB);
#pragma unroll
    for (int v = 0; v < VEC; ++v) acc[v] += pA * xA[v] + pB * xB[v];
  }
  if (i < end) {
    int sA = srcs[i];
    float pA = __expf(lrelu(a_s[(size_t)sA * 4 + h] + adn) - m);
    s += pA;
    float xA[VEC];
    load_bf<VEC>(xs + (size_t)sA * HC + h * CH + c, xA);
#pragma unroll
    for (int v = 0; v < VEC; ++v) acc[v] += pA * xA[v];
  }

  float r = s > 0.f ? 1.f / s : 0.f;
  size_t obase = (size_t)n * HC + h * CH + c;
  float sk[VEC];
  load_bf<VEC>(skip + obase, sk);
#pragma unroll
  for (int v = 0; v < VEC; ++v) {
    float val = acc[v] * r + bias[h * CH + c + v] + sk[v];
    if (RELU) val = fmaxf(val, 0.f);
    if (OUT_BF16) ((ushort*)outv)[obase + v] = f2bf(val);
    else          ((float*)outv)[obase + v] = val;
  }
}

// ---------------- host launch ----------------
extern "C" void kernel_launch(void* const* d_in, const int* in_sizes, int n_in,
                              void* d_out, int out_size, void* d_ws, size_t ws_size,
                              hipStream_t stream) {
  const float* x      = (const float*)d_in[0];
  const int*   ei     = (const int*)d_in[1];
  const float* W_rna  = (const float*)d_in[3];
  const float* b_rna  = (const float*)d_in[4];
  const float* W_prot = (const float*)d_in[5];
  const float* b_prot = (const float*)d_in[6];
  const float* W1s    = (const float*)d_in[7];
  const float* W1d    = (const float*)d_in[8];
  const float* at1s   = (const float*)d_in[9];
  const float* at1d   = (const float*)d_in[10];
  const float* bias1  = (const float*)d_in[11];
  const float* Wl1    = (const float*)d_in[12];
  const float* bl1    = (const float*)d_in[13];
  const float* W2s    = (const float*)d_in[14];
  const float* W2d    = (const float*)d_in[15];
  const float* at2s   = (const float*)d_in[16];
  const float* at2d   = (const float*)d_in[17];
  const float* bias2  = (const float*)d_in[18];
  const float* Wl2    = (const float*)d_in[19];
  const float* bl2    = (const float*)d_in[20];

  const int N = in_sizes[0] / D_IN;   // 40000
  const int E = in_sizes[1] / 2;      // 640000
  const int* srcv = ei;
  const int* dstv = ei + E;

  char* ws = (char*)d_ws;
  size_t o = 0;
  auto carve = [&](size_t bytes) {
    void* p = ws + o;
    o += (bytes + 255) & ~(size_t)255;
    return p;
  };
  int* deg    = (int*)carve((size_t)N * 4);
  int* offp   = (int*)carve((size_t)(N + 1) * 4);
  int* cur    = (int*)carve((size_t)N * 4);
  int* srcs   = (int*)carve((size_t)E * 4);
  float* a_s  = (float*)carve((size_t)N * 4 * 4);
  float* a_d  = (float*)carve((size_t)N * 4 * 4);
  ushort* BTr = (ushort*)carve(64 * 1024 * 2);
  ushort* BTp = (ushort*)carve(64 * 320 * 2);
  ushort* BT1 = (ushort*)carve(512 * 128 * 2);
  ushort* BT2 = (ushort*)carve(256 * 256 * 2);
  ushort* BTA1 = (ushort*)carve(64 * 128 * 2);
  ushort* BTA2 = (ushort*)carve(64 * 256 * 2);
  float* biasL1 = (float*)carve(512 * 4);
  float* biasL2 = (float*)carve(256 * 4);
  ushort* h0  = (ushort*)carve((size_t)N * HDIM * 2);
  ushort* xs1 = (ushort*)carve((size_t)N * HC1 * 2);
  ushort* z1  = (ushort*)carve((size_t)N * HC1 * 2);
  ushort* h1  = (ushort*)carve((size_t)N * HC1 * 2);
  ushort* xs2 = h0;   // h0 dead after layer-1 gemm (att folded in)
  ushort* z2  = z1;   // z1 dead after gat_fused1
  float* out = (float*)d_out;

  // 1. counting-sort edges by dst
  zero_i32<<<(N + 255) / 256, 256, 0, stream>>>(deg, N);
  hist_kernel<<<(E + 255) / 256, 256, 0, stream>>>(dstv, deg, E);
  scan_kernel<<<1, 1024, 0, stream>>>(deg, offp, cur, N);
  scatter_kernel<<<(E + 255) / 256, 256, 0, stream>>>(srcv, dstv, cur, srcs, E);
  // 2. fold att (-> BTA tiles) + weight conversion
  fold_att_kernel<<<8, 256, 0, stream>>>(W1s, W1d, at1s, at1d, W2s, W2d, at2s, at2d,
                                         BTA1, BTA2);
  convert_weights<<<256, 256, 0, stream>>>(W_rna, W_prot, W1s, Wl1, W2s, Wl2,
                                           bias1, bl1, bias2, bl2,
                                           BTr, BTp, BT1, BT2, biasL1, biasL2);
  // 3. embedding -> h0[N,128] bf16
  embed_gemm<<<dim3(2, N / 64), 256, 0, stream>>>(x, BTr, BTp, b_rna, b_prot, h0);
  // 4. layer-1: [xs1|z1] = h0 @ [W1s|Wl1] (+bias) and a_s/a_d (att block), bf16
  layer_gemm<<<dim3(9, N / 64), 256, 0, stream>>>(h0, HDIM, BT1, biasL1, xs1, z1, HC1,
                                                  BTA1, a_s, a_d);
  // 5. fused softmax+aggregate -> h1 = relu(agg + bias1 + z1), bf16
  gat_fused_kernel<CH1, 4, true, true><<<N / 4, 256, 0, stream>>>(offp, srcs, a_s, a_d, xs1,
                                                                  bias1, z1, h1, N);
  // 6. layer-2
  layer_gemm<<<dim3(5, N / 64), 256, 0, stream>>>(h1, HC1, BT2, biasL2, xs2, z2, HC2,
                                                  BTA2, a_s, a_d);
  gat_fused_kernel<CH2, 2, false, false><<<N / 4, 256, 0, stream>>>(offp, srcs, a_s, a_d, xs2,
                                                                    bias2, z2, out, N);
}

// Round 6
// 700.741 us; speedup vs baseline: 1.2127x; 1.0086x over previous
//
#include <hip/hip_runtime.h>
#include <hip/hip_bf16.h>
#include <stdint.h>

// GraRPINet: 2-layer GAT. N=40000 nodes, E=640000 edges.
// R3: all GEMMs -> bf16 MFMA (16x16x32), weights pre-transposed bf16 BT[n][k].
// R4/R6/R7 (reverted): LDS-free embed, split-K partials, BM=32 all regressed --
// embed's R5 config is a local optimum (123us). Lesson: zero extra DRAM traffic.
// R8 (WIN, 762->707): attn_proj folded into layer_gemm as an extra col-block
// (bf16 hi+lo att rows -> fp32 logits); edge_softmax fused into aggregate.
// R9: layer_gemm col-grouping G=2: each block computes 128 cols (2 B-tiles) per
// staged A-tile. L1 grid (9,625)->(5,625), L2 (5,625)->(3,625): halves block-iters
// and barrier-groups, doubles MFMA per barrier. LDS 27.6KB -> 5 blocks/CU.

#define HEADS 4
#define CH1   64
#define CH2   32
#define HC1   256
#define HC2   128

static constexpr int D_RNA  = 1000;
static constexpr int D_PROT = 300;
static constexpr int D_IN   = 1300;
static constexpr int HDIM   = 128;  // 2H

typedef __bf16 bf16x8 __attribute__((ext_vector_type(8)));
typedef float  f32x4  __attribute__((ext_vector_type(4)));
typedef unsigned short ushort;

__device__ __forceinline__ float lrelu(float x) { return x >= 0.f ? x : 0.2f * x; }
__device__ __forceinline__ float bf2f(unsigned int u16) {
  return __uint_as_float(u16 << 16);
}
__device__ __forceinline__ ushort f2bf(float f) {
  union { float f; unsigned int u; } x; x.f = f;
  unsigned int r = x.u + 0x7fffu + ((x.u >> 16) & 1u);
  return (ushort)(r >> 16);
}

// ---------------- small utility kernels ----------------
__global__ void zero_i32(int* p, int n) {
  int i = blockIdx.x * 256 + threadIdx.x;
  if (i < n) p[i] = 0;
}

__global__ void hist_kernel(const int* __restrict__ dstv, int* __restrict__ deg, int E) {
  int i = blockIdx.x * 256 + threadIdx.x;
  if (i < E) atomicAdd(&deg[dstv[i]], 1);
}

__global__ void scan_kernel(const int* __restrict__ deg, int* __restrict__ off,
                            int* __restrict__ cur, int n) {
  __shared__ int s[1024];
  int tid = threadIdx.x;
  const int CHK = (n + 1023) / 1024;
  int base = tid * CHK;
  int sum = 0;
  for (int j = 0; j < CHK; ++j) {
    int i = base + j;
    if (i < n) sum += deg[i];
  }
  s[tid] = sum;
  __syncthreads();
  for (int o = 1; o < 1024; o <<= 1) {
    int t = (tid >= o) ? s[tid - o] : 0;
    __syncthreads();
    s[tid] += t;
    __syncthreads();
  }
  int run = s[tid] - sum;
  for (int j = 0; j < CHK; ++j) {
    int i = base + j;
    if (i < n) {
      off[i] = run; cur[i] = run;
      run += deg[i];
    }
  }
  if (tid == 1023) off[n] = s[1023];
}

__global__ void scatter_kernel(const int* __restrict__ srcv, const int* __restrict__ dstv,
                               int* __restrict__ cur, int* __restrict__ srcs, int E) {
  int i = blockIdx.x * 256 + threadIdx.x;
  if (i < E) {
    int d = dstv[i];
    int pos = atomicAdd(&cur[d], 1);
    srcs[pos] = srcv[i];
  }
}

// fold att vectors v[k,h] = sum_c W[k, h*CH+c]*att[h,c], then pack as GEMM B-tiles:
// BTA[64][K]: rows 0..3 = vs_hi, 4..7 = vs_lo, 8..11 = vd_hi, 12..15 = vd_lo,
// rows 16..63 = 0. hi/lo bf16 split keeps logits at ~fp32 precision.
__global__ void fold_att_kernel(const float* __restrict__ W1s, const float* __restrict__ W1d,
                                const float* __restrict__ at1s, const float* __restrict__ at1d,
                                const float* __restrict__ W2s, const float* __restrict__ W2d,
                                const float* __restrict__ at2s, const float* __restrict__ at2d,
                                ushort* __restrict__ BTA1, ushort* __restrict__ BTA2) {
  int tid = blockIdx.x * blockDim.x + threadIdx.x;
  int stride = gridDim.x * blockDim.x;
  for (int o = tid; o < HDIM * HEADS; o += stride) {
    int k = o >> 2, h = o & 3;
    float ss = 0.f, sd = 0.f;
    for (int c = 0; c < CH1; ++c) {
      ss += W1s[k * HC1 + h * CH1 + c] * at1s[h * CH1 + c];
      sd += W1d[k * HC1 + h * CH1 + c] * at1d[h * CH1 + c];
    }
    ushort sh = f2bf(ss), dh = f2bf(sd);
    BTA1[(0 + h) * HDIM + k] = sh;
    BTA1[(4 + h) * HDIM + k] = f2bf(ss - bf2f(sh));
    BTA1[(8 + h) * HDIM + k] = dh;
    BTA1[(12 + h) * HDIM + k] = f2bf(sd - bf2f(dh));
  }
  for (int o = tid; o < HC1 * HEADS; o += stride) {
    int k = o >> 2, h = o & 3;
    float ss = 0.f, sd = 0.f;
    for (int c = 0; c < CH2; ++c) {
      ss += W2s[k * HC2 + h * CH2 + c] * at2s[h * CH2 + c];
      sd += W2d[k * HC2 + h * CH2 + c] * at2d[h * CH2 + c];
    }
    ushort sh = f2bf(ss), dh = f2bf(sd);
    BTA2[(0 + h) * HC1 + k] = sh;
    BTA2[(4 + h) * HC1 + k] = f2bf(ss - bf2f(sh));
    BTA2[(8 + h) * HC1 + k] = dh;
    BTA2[(12 + h) * HC1 + k] = f2bf(sd - bf2f(dh));
  }
  for (int i = tid; i < 48 * HDIM; i += stride) BTA1[16 * HDIM + i] = 0;
  for (int i = tid; i < 48 * HC1; i += stride) BTA2[16 * HC1 + i] = 0;
}

// ---------------- weight preprocessing: transpose + bf16 ----------------
// BTr[64][1024] (k>=1000 zero), BTp[64][320] (k>=300 zero),
// BT1[512][128] = [W1s|Wl1]^T, BT2[256][256] = [W2s|Wl2]^T, concat biases.
__global__ void convert_weights(const float* __restrict__ W_rna, const float* __restrict__ W_prot,
                                const float* __restrict__ W1s, const float* __restrict__ Wl1,
                                const float* __restrict__ W2s, const float* __restrict__ Wl2,
                                const float* __restrict__ b1, const float* __restrict__ bl1,
                                const float* __restrict__ b2, const float* __restrict__ bl2,
                                ushort* BTr, ushort* BTp, ushort* BT1, ushort* BT2,
                                float* biasL1, float* biasL2) {
  int tid = blockIdx.x * blockDim.x + threadIdx.x;
  int stride = gridDim.x * blockDim.x;
  for (int i = tid; i < 64 * 1024; i += stride) {
    int n = i >> 10, k = i & 1023;
    BTr[i] = (k < D_RNA) ? f2bf(W_rna[k * 64 + n]) : 0;
  }
  for (int i = tid; i < 64 * 320; i += stride) {
    int n = i / 320, k = i - n * 320;
    BTp[i] = (k < D_PROT) ? f2bf(W_prot[k * 64 + n]) : 0;
  }
  for (int i = tid; i < 512 * 128; i += stride) {
    int n = i >> 7, k = i & 127;
    BT1[i] = f2bf(n < 256 ? W1s[k * 256 + n] : Wl1[k * 256 + n - 256]);
  }
  for (int i = tid; i < 256 * 256; i += stride) {
    int n = i >> 8, k = i & 255;
    BT2[i] = f2bf(n < 128 ? W2s[k * 128 + n] : Wl2[k * 128 + n - 128]);
  }
  for (int i = tid; i < 512; i += stride) biasL1[i] = (i < 256) ? b1[i] : bl1[i - 256];
  for (int i = tid; i < 256; i += stride) biasL2[i] = (i < 128) ? b2[i] : bl2[i - 128];
}

#define LDK 72  // padded k-stride (shorts) for 64-wide k tiles: 144B rows -> 2-way-only conflicts

__device__ __forceinline__ f32x4 mfma_bf16(bf16x8 a, bf16x8 b, f32x4 c) {
  return __builtin_amdgcn_mfma_f32_16x16x32_bf16(a, b, c, 0, 0, 0);
}

// ---------------- embedding MFMA GEMM: h0[N,128] bf16 (R5-exact, local optimum) -------
__launch_bounds__(256)
__global__ void embed_gemm(const float* __restrict__ x,
                           const ushort* __restrict__ BTr, const ushort* __restrict__ BTp,
                           const float* __restrict__ b_rna, const float* __restrict__ b_prot,
                           ushort* __restrict__ h0) {
  const bool prot = (blockIdx.x == 1);
  const int Kpad = prot ? 320 : 1024;
  const int acol = prot ? D_RNA : 0;
  const ushort* BT = prot ? BTp : BTr;
  const float* bias = prot ? b_prot : b_rna;
  const int r0 = blockIdx.y * 64;

  __shared__ ushort As[64 * LDK];
  __shared__ ushort Bs[64 * LDK];
  int tid = threadIdx.x;
  int wave = tid >> 6, lane = tid & 63;
  int quad = lane >> 4, lr = lane & 15;
  f32x4 acc[4];
#pragma unroll
  for (int c = 0; c < 4; ++c) acc[c] = (f32x4){0.f, 0.f, 0.f, 0.f};

  int srow = tid >> 2, skq = (tid & 3) * 16;
  const float* aprow = x + (size_t)(r0 + srow) * D_IN;
  const ushort* bprow = BT + (size_t)srow * Kpad;

  float4 fa[4];
  uint4 fb0, fb1;

  auto loadA = [&](int k0) {
#pragma unroll
    for (int q = 0; q < 4; ++q) {
      int kg = acol + k0 + skq + q * 4;
      fa[q] = (kg + 4 <= D_IN) ? *(const float4*)(aprow + kg)
                               : make_float4(0.f, 0.f, 0.f, 0.f);
    }
  };
  auto loadB = [&](int k0) {
    const ushort* bp = bprow + k0 + skq;
    fb0 = *(const uint4*)bp;
    fb1 = *(const uint4*)(bp + 8);
  };

  loadA(0);
  loadB(0);

  for (int k0 = 0; k0 < Kpad; k0 += 64) {
    {
      ushort tmp[16];
#pragma unroll
      for (int q = 0; q < 4; ++q) {
        tmp[q * 4 + 0] = f2bf(fa[q].x); tmp[q * 4 + 1] = f2bf(fa[q].y);
        tmp[q * 4 + 2] = f2bf(fa[q].z); tmp[q * 4 + 3] = f2bf(fa[q].w);
      }
      *(uint4*)&As[srow * LDK + skq] = *(const uint4*)&tmp[0];
      *(uint4*)&As[srow * LDK + skq + 8] = *(const uint4*)&tmp[8];
      *(uint4*)&Bs[srow * LDK + skq] = fb0;
      *(uint4*)&Bs[srow * LDK + skq + 8] = fb1;
    }
    __syncthreads();
    if (k0 + 64 < Kpad) {
      loadA(k0 + 64);
      loadB(k0 + 64);
    }
    int arow = wave * 16 + lr;
    bf16x8 a0 = *(const bf16x8*)&As[arow * LDK + quad * 8];
    bf16x8 a1 = *(const bf16x8*)&As[arow * LDK + 32 + quad * 8];
#pragma unroll
    for (int c = 0; c < 4; ++c) {
      bf16x8 b0 = *(const bf16x8*)&Bs[(c * 16 + lr) * LDK + quad * 8];
      bf16x8 b1 = *(const bf16x8*)&Bs[(c * 16 + lr) * LDK + 32 + quad * 8];
      acc[c] = mfma_bf16(a0, b0, acc[c]);
      acc[c] = mfma_bf16(a1, b1, acc[c]);
    }
    __syncthreads();
  }
  int colb = prot ? 64 : 0;
#pragma unroll
  for (int c = 0; c < 4; ++c) {
#pragma unroll
    for (int j = 0; j < 4; ++j) {
      int row = r0 + wave * 16 + quad * 4 + j;
      int col = c * 16 + lr;
      h0[(size_t)row * HDIM + colb + col] = f2bf(acc[c][j] + bias[col]);
    }
  }
}

// ---------------- layer MFMA GEMM (col-group G=2) + folded attention logits ----------
// grid (ngroups+1, N/64). Regular block x: cols [x*128, x*128+128) = 2 B-tiles sharing
// one staged A-tile. Last x-block uses BTA (single tile) and writes fp32 a_s/a_d:
// out col t(0..3) hi + col t+4 lo summed via shfl_xor(4) -> a_s; cols 8..15 -> a_d.
__launch_bounds__(256)
__global__ void layer_gemm(const ushort* __restrict__ A, int K,
                           const ushort* __restrict__ BT, const float* __restrict__ bias,
                           ushort* __restrict__ out0, ushort* __restrict__ out1, int halfw,
                           const ushort* __restrict__ BTA,
                           float* __restrict__ a_s, float* __restrict__ a_d) {
  const bool att = (blockIdx.x == gridDim.x - 1);
  const int cb = att ? 0 : blockIdx.x * 128;
  const int r0 = blockIdx.y * 64;
  __shared__ ushort As[64 * LDK];
  __shared__ ushort Bs[2][64 * LDK];
  int tid = threadIdx.x;
  int wave = tid >> 6, lane = tid & 63;
  int quad = lane >> 4, lr = lane & 15;
  f32x4 acc[8];
#pragma unroll
  for (int c = 0; c < 8; ++c) acc[c] = (f32x4){0.f, 0.f, 0.f, 0.f};

  int srow = tid >> 2, skq = (tid & 3) * 16;
  const ushort* aprow = A + (size_t)(r0 + srow) * K;
  const ushort* bprow0 = att ? (BTA + (size_t)srow * K)
                             : (BT + (size_t)(cb + srow) * K);
  const ushort* bprow1 = BT + (size_t)(cb + 64 + srow) * K;   // unused when att

  uint4 fa0, fa1, fb00, fb01, fb10, fb11;
  auto loadAB = [&](int k0) {
    const ushort* ap = aprow + k0 + skq;
    fa0 = *(const uint4*)ap;
    fa1 = *(const uint4*)(ap + 8);
    const ushort* bp0 = bprow0 + k0 + skq;
    fb00 = *(const uint4*)bp0;
    fb01 = *(const uint4*)(bp0 + 8);
    if (!att) {
      const ushort* bp1 = bprow1 + k0 + skq;
      fb10 = *(const uint4*)bp1;
      fb11 = *(const uint4*)(bp1 + 8);
    }
  };

  loadAB(0);

  for (int k0 = 0; k0 < K; k0 += 64) {
    *(uint4*)&As[srow * LDK + skq] = fa0;
    *(uint4*)&As[srow * LDK + skq + 8] = fa1;
    *(uint4*)&Bs[0][srow * LDK + skq] = fb00;
    *(uint4*)&Bs[0][srow * LDK + skq + 8] = fb01;
    if (!att) {
      *(uint4*)&Bs[1][srow * LDK + skq] = fb10;
      *(uint4*)&Bs[1][srow * LDK + skq + 8] = fb11;
    }
    __syncthreads();
    if (k0 + 64 < K) loadAB(k0 + 64);
    int arow = wave * 16 + lr;
    bf16x8 a0 = *(const bf16x8*)&As[arow * LDK + quad * 8];
    bf16x8 a1 = *(const bf16x8*)&As[arow * LDK + 32 + quad * 8];
#pragma unroll
    for (int c = 0; c < 4; ++c) {
      bf16x8 b0 = *(const bf16x8*)&Bs[0][(c * 16 + lr) * LDK + quad * 8];
      bf16x8 b1 = *(const bf16x8*)&Bs[0][(c * 16 + lr) * LDK + 32 + quad * 8];
      acc[c] = mfma_bf16(a0, b0, acc[c]);
      acc[c] = mfma_bf16(a1, b1, acc[c]);
    }
    if (!att) {
#pragma unroll
      for (int c = 0; c < 4; ++c) {
        bf16x8 b0 = *(const bf16x8*)&Bs[1][(c * 16 + lr) * LDK + quad * 8];
        bf16x8 b1 = *(const bf16x8*)&Bs[1][(c * 16 + lr) * LDK + 32 + quad * 8];
        acc[4 + c] = mfma_bf16(a0, b0, acc[4 + c]);
        acc[4 + c] = mfma_bf16(a1, b1, acc[4 + c]);
      }
    }
    __syncthreads();
  }
  if (att) {
#pragma unroll
    for (int j = 0; j < 4; ++j) {
      int row = r0 + wave * 16 + quad * 4 + j;
      float v0 = acc[0][j];
      float sum = v0 + __shfl_xor(v0, 4);   // hi + lo partner
      if (lr < 4)                    a_s[(size_t)row * 4 + lr] = sum;
      else if (lr >= 8 && lr < 12)   a_d[(size_t)row * 4 + (lr - 8)] = sum;
    }
    return;
  }
#pragma unroll
  for (int t = 0; t < 2; ++t) {
#pragma unroll
    for (int c = 0; c < 4; ++c) {
#pragma unroll
      for (int j = 0; j < 4; ++j) {
        int row = r0 + wave * 16 + quad * 4 + j;
        int cg = cb + t * 64 + c * 16 + lr;
        ushort v = f2bf(acc[t * 4 + c][j] + bias[cg]);
        if (cg < halfw) out0[(size_t)row * halfw + cg] = v;
        else            out1[(size_t)row * halfw + cg - halfw] = v;
      }
    }
  }
}

// ---------------- fused segment softmax + weighted aggregate + bias + skip (+relu) ----
template <int VEC>
__device__ __forceinline__ void load_bf(const ushort* p, float* out);
template <>
__device__ __forceinline__ void load_bf<4>(const ushort* p, float* out) {
  uint2 q = *(const uint2*)p;
  out[0] = bf2f(q.x & 0xffffu); out[1] = bf2f(q.x >> 16);
  out[2] = bf2f(q.y & 0xffffu); out[3] = bf2f(q.y >> 16);
}
template <>
__device__ __forceinline__ void load_bf<2>(const ushort* p, float* out) {
  unsigned int q = *(const unsigned int*)p;
  out[0] = bf2f(q & 0xffffu); out[1] = bf2f(q >> 16);
}

template <int CH, int VEC, bool RELU, bool OUT_BF16>
__launch_bounds__(256)
__global__ void gat_fused_kernel(const int* __restrict__ off, const int* __restrict__ srcs,
                                 const float* __restrict__ a_s, const float* __restrict__ a_d,
                                 const ushort* __restrict__ xs,
                                 const float* __restrict__ bias,
                                 const ushort* __restrict__ skip,
                                 void* __restrict__ outv, int N) {
  const int HC = 4 * CH;
  int wave = threadIdx.x >> 6, lane = threadIdx.x & 63;
  int n = blockIdx.x * 4 + wave;
  if (n >= N) return;
  int h = lane >> 4;
  int c = (lane & 15) * VEC;
  int s0 = off[n], end = off[n + 1];
  float adn = a_d[(size_t)n * 4 + h];

  // pass A: max logit per head
  float m = -1e30f;
  int i = s0;
  for (; i + 4 <= end; i += 4) {
    float e0 = a_s[(size_t)srcs[i] * 4 + h];
    float e1 = a_s[(size_t)srcs[i + 1] * 4 + h];
    float e2 = a_s[(size_t)srcs[i + 2] * 4 + h];
    float e3 = a_s[(size_t)srcs[i + 3] * 4 + h];
    m = fmaxf(m, fmaxf(fmaxf(lrelu(e0 + adn), lrelu(e1 + adn)),
                       fmaxf(lrelu(e2 + adn), lrelu(e3 + adn))));
  }
  for (; i < end; ++i) m = fmaxf(m, lrelu(a_s[(size_t)srcs[i] * 4 + h] + adn));

  // pass B: exp + sum + weighted accumulate
  float s = 0.f;
  float acc[VEC];
#pragma unroll
  for (int v = 0; v < VEC; ++v) acc[v] = 0.f;
  for (i = s0; i + 2 <= end; i += 2) {
    int sA = srcs[i], sB = srcs[i + 1];
    float pA = __expf(lrelu(a_s[(size_t)sA * 4 + h] + adn) - m);
    float pB = __expf(lrelu(a_s[(size_t)sB * 4 + h] + adn) - m);
    s += pA + pB;
    float xA[VEC], xB[VEC];
    load_bf<VEC>(xs + (size_t)sA * HC + h * CH + c, xA);
    load_bf<VEC>(xs + (size_t)sB * HC + h * CH + c, xB);
#pragma unroll
    for (int v = 0; v < VEC; ++v) acc[v] += pA * xA[v] + pB * xB[v];
  }
  if (i < end) {
    int sA = srcs[i];
    float pA = __expf(lrelu(a_s[(size_t)sA * 4 + h] + adn) - m);
    s += pA;
    float xA[VEC];
    load_bf<VEC>(xs + (size_t)sA * HC + h * CH + c, xA);
#pragma unroll
    for (int v = 0; v < VEC; ++v) acc[v] += pA * xA[v];
  }

  float r = s > 0.f ? 1.f / s : 0.f;
  size_t obase = (size_t)n * HC + h * CH + c;
  float sk[VEC];
  load_bf<VEC>(skip + obase, sk);
#pragma unroll
  for (int v = 0; v < VEC; ++v) {
    float val = acc[v] * r + bias[h * CH + c + v] + sk[v];
    if (RELU) val = fmaxf(val, 0.f);
    if (OUT_BF16) ((ushort*)outv)[obase + v] = f2bf(val);
    else          ((float*)outv)[obase + v] = val;
  }
}

// ---------------- host launch ----------------
extern "C" void kernel_launch(void* const* d_in, const int* in_sizes, int n_in,
                              void* d_out, int out_size, void* d_ws, size_t ws_size,
                              hipStream_t stream) {
  const float* x      = (const float*)d_in[0];
  const int*   ei     = (const int*)d_in[1];
  const float* W_rna  = (const float*)d_in[3];
  const float* b_rna  = (const float*)d_in[4];
  const float* W_prot = (const float*)d_in[5];
  const float* b_prot = (const float*)d_in[6];
  const float* W1s    = (const float*)d_in[7];
  const float* W1d    = (const float*)d_in[8];
  const float* at1s   = (const float*)d_in[9];
  const float* at1d   = (const float*)d_in[10];
  const float* bias1  = (const float*)d_in[11];
  const float* Wl1    = (const float*)d_in[12];
  const float* bl1    = (const float*)d_in[13];
  const float* W2s    = (const float*)d_in[14];
  const float* W2d    = (const float*)d_in[15];
  const float* at2s   = (const float*)d_in[16];
  const float* at2d   = (const float*)d_in[17];
  const float* bias2  = (const float*)d_in[18];
  const float* Wl2    = (const float*)d_in[19];
  const float* bl2    = (const float*)d_in[20];

  const int N = in_sizes[0] / D_IN;   // 40000
  const int E = in_sizes[1] / 2;      // 640000
  const int* srcv = ei;
  const int* dstv = ei + E;

  char* ws = (char*)d_ws;
  size_t o = 0;
  auto carve = [&](size_t bytes) {
    void* p = ws + o;
    o += (bytes + 255) & ~(size_t)255;
    return p;
  };
  int* deg    = (int*)carve((size_t)N * 4);
  int* offp   = (int*)carve((size_t)(N + 1) * 4);
  int* cur    = (int*)carve((size_t)N * 4);
  int* srcs   = (int*)carve((size_t)E * 4);
  float* a_s  = (float*)carve((size_t)N * 4 * 4);
  float* a_d  = (float*)carve((size_t)N * 4 * 4);
  ushort* BTr = (ushort*)carve(64 * 1024 * 2);
  ushort* BTp = (ushort*)carve(64 * 320 * 2);
  ushort* BT1 = (ushort*)carve(512 * 128 * 2);
  ushort* BT2 = (ushort*)carve(256 * 256 * 2);
  ushort* BTA1 = (ushort*)carve(64 * 128 * 2);
  ushort* BTA2 = (ushort*)carve(64 * 256 * 2);
  float* biasL1 = (float*)carve(512 * 4);
  float* biasL2 = (float*)carve(256 * 4);
  ushort* h0  = (ushort*)carve((size_t)N * HDIM * 2);
  ushort* xs1 = (ushort*)carve((size_t)N * HC1 * 2);
  ushort* z1  = (ushort*)carve((size_t)N * HC1 * 2);
  ushort* h1  = (ushort*)carve((size_t)N * HC1 * 2);
  ushort* xs2 = h0;   // h0 dead after layer-1 gemm (att folded in)
  ushort* z2  = z1;   // z1 dead after gat_fused1
  float* out = (float*)d_out;

  // 1. counting-sort edges by dst
  zero_i32<<<(N + 255) / 256, 256, 0, stream>>>(deg, N);
  hist_kernel<<<(E + 255) / 256, 256, 0, stream>>>(dstv, deg, E);
  scan_kernel<<<1, 1024, 0, stream>>>(deg, offp, cur, N);
  scatter_kernel<<<(E + 255) / 256, 256, 0, stream>>>(srcv, dstv, cur, srcs, E);
  // 2. fold att (-> BTA tiles) + weight conversion
  fold_att_kernel<<<8, 256, 0, stream>>>(W1s, W1d, at1s, at1d, W2s, W2d, at2s, at2d,
                                         BTA1, BTA2);
  convert_weights<<<256, 256, 0, stream>>>(W_rna, W_prot, W1s, Wl1, W2s, Wl2,
                                           bias1, bl1, bias2, bl2,
                                           BTr, BTp, BT1, BT2, biasL1, biasL2);
  // 3. embedding -> h0[N,128] bf16
  embed_gemm<<<dim3(2, N / 64), 256, 0, stream>>>(x, BTr, BTp, b_rna, b_prot, h0);
  // 4. layer-1: [xs1|z1] = h0 @ [W1s|Wl1] (+bias) and a_s/a_d (att block), bf16
  //    4 col-groups of 128 + att block
  layer_gemm<<<dim3(5, N / 64), 256, 0, stream>>>(h0, HDIM, BT1, biasL1, xs1, z1, HC1,
                                                  BTA1, a_s, a_d);
  // 5. fused softmax+aggregate -> h1 = relu(agg + bias1 + z1), bf16
  gat_fused_kernel<CH1, 4, true, true><<<N / 4, 256, 0, stream>>>(offp, srcs, a_s, a_d, xs1,
                                                                  bias1, z1, h1, N);
  // 6. layer-2: 2 col-groups of 128 + att block
  layer_gemm<<<dim3(3, N / 64), 256, 0, stream>>>(h1, HC1, BT2, biasL2, xs2, z2, HC2,
                                                  BTA2, a_s, a_d);
  gat_fused_kernel<CH2, 2, false, false><<<N / 4, 256, 0, stream>>>(offp, srcs, a_s, a_d, xs2,
                                                                    bias2, z2, out, N);
}

// Round 7
// 655.458 us; speedup vs baseline: 1.2965x; 1.0691x over previous
//
#include <hip/hip_runtime.h>
#include <hip/hip_bf16.h>
#include <stdint.h>

// GraRPINet: 2-layer GAT. N=40000 nodes, E=640000 edges.
// R3: all GEMMs -> bf16 MFMA (16x16x32), weights pre-transposed bf16 BT[n][k].
// R4/R6/R7 (reverted): LDS-free embed, split-K partials, BM=32 all regressed --
// embed's R5 config is a local optimum (~124us). Lesson: zero extra DRAM traffic.
// R8 (WIN, 762->707): attn_proj folded into layer_gemm extra col-block; edge_softmax
// fused into aggregate.
// R9 (neutral, 707->701): layer_gemm col-group G=2 -- layer GEMMs were small.
// R10: gat_fused rewritten: single-pass ONLINE softmax (deletes the max-pass edge
// traversal; rescale only on running-max update, 2-edge unrolled) + VEC=8 lanes
// (16B uint4 gathers; CH1: 8 lanes/head, 2 nodes/wave; CH2: 4 lanes/head, 4/wave).

#define HEADS 4
#define CH1   64
#define CH2   32
#define HC1   256
#define HC2   128

static constexpr int D_RNA  = 1000;
static constexpr int D_PROT = 300;
static constexpr int D_IN   = 1300;
static constexpr int HDIM   = 128;  // 2H

typedef __bf16 bf16x8 __attribute__((ext_vector_type(8)));
typedef float  f32x4  __attribute__((ext_vector_type(4)));
typedef unsigned short ushort;

__device__ __forceinline__ float lrelu(float x) { return x >= 0.f ? x : 0.2f * x; }
__device__ __forceinline__ float bf2f(unsigned int u16) {
  return __uint_as_float(u16 << 16);
}
__device__ __forceinline__ ushort f2bf(float f) {
  union { float f; unsigned int u; } x; x.f = f;
  unsigned int r = x.u + 0x7fffu + ((x.u >> 16) & 1u);
  return (ushort)(r >> 16);
}

// ---------------- small utility kernels ----------------
__global__ void zero_i32(int* p, int n) {
  int i = blockIdx.x * 256 + threadIdx.x;
  if (i < n) p[i] = 0;
}

__global__ void hist_kernel(const int* __restrict__ dstv, int* __restrict__ deg, int E) {
  int i = blockIdx.x * 256 + threadIdx.x;
  if (i < E) atomicAdd(&deg[dstv[i]], 1);
}

__global__ void scan_kernel(const int* __restrict__ deg, int* __restrict__ off,
                            int* __restrict__ cur, int n) {
  __shared__ int s[1024];
  int tid = threadIdx.x;
  const int CHK = (n + 1023) / 1024;
  int base = tid * CHK;
  int sum = 0;
  for (int j = 0; j < CHK; ++j) {
    int i = base + j;
    if (i < n) sum += deg[i];
  }
  s[tid] = sum;
  __syncthreads();
  for (int o = 1; o < 1024; o <<= 1) {
    int t = (tid >= o) ? s[tid - o] : 0;
    __syncthreads();
    s[tid] += t;
    __syncthreads();
  }
  int run = s[tid] - sum;
  for (int j = 0; j < CHK; ++j) {
    int i = base + j;
    if (i < n) {
      off[i] = run; cur[i] = run;
      run += deg[i];
    }
  }
  if (tid == 1023) off[n] = s[1023];
}

__global__ void scatter_kernel(const int* __restrict__ srcv, const int* __restrict__ dstv,
                               int* __restrict__ cur, int* __restrict__ srcs, int E) {
  int i = blockIdx.x * 256 + threadIdx.x;
  if (i < E) {
    int d = dstv[i];
    int pos = atomicAdd(&cur[d], 1);
    srcs[pos] = srcv[i];
  }
}

// fold att vectors v[k,h] = sum_c W[k, h*CH+c]*att[h,c], then pack as GEMM B-tiles:
// BTA[64][K]: rows 0..3 = vs_hi, 4..7 = vs_lo, 8..11 = vd_hi, 12..15 = vd_lo,
// rows 16..63 = 0. hi/lo bf16 split keeps logits at ~fp32 precision.
__global__ void fold_att_kernel(const float* __restrict__ W1s, const float* __restrict__ W1d,
                                const float* __restrict__ at1s, const float* __restrict__ at1d,
                                const float* __restrict__ W2s, const float* __restrict__ W2d,
                                const float* __restrict__ at2s, const float* __restrict__ at2d,
                                ushort* __restrict__ BTA1, ushort* __restrict__ BTA2) {
  int tid = blockIdx.x * blockDim.x + threadIdx.x;
  int stride = gridDim.x * blockDim.x;
  for (int o = tid; o < HDIM * HEADS; o += stride) {
    int k = o >> 2, h = o & 3;
    float ss = 0.f, sd = 0.f;
    for (int c = 0; c < CH1; ++c) {
      ss += W1s[k * HC1 + h * CH1 + c] * at1s[h * CH1 + c];
      sd += W1d[k * HC1 + h * CH1 + c] * at1d[h * CH1 + c];
    }
    ushort sh = f2bf(ss), dh = f2bf(sd);
    BTA1[(0 + h) * HDIM + k] = sh;
    BTA1[(4 + h) * HDIM + k] = f2bf(ss - bf2f(sh));
    BTA1[(8 + h) * HDIM + k] = dh;
    BTA1[(12 + h) * HDIM + k] = f2bf(sd - bf2f(dh));
  }
  for (int o = tid; o < HC1 * HEADS; o += stride) {
    int k = o >> 2, h = o & 3;
    float ss = 0.f, sd = 0.f;
    for (int c = 0; c < CH2; ++c) {
      ss += W2s[k * HC2 + h * CH2 + c] * at2s[h * CH2 + c];
      sd += W2d[k * HC2 + h * CH2 + c] * at2d[h * CH2 + c];
    }
    ushort sh = f2bf(ss), dh = f2bf(sd);
    BTA2[(0 + h) * HC1 + k] = sh;
    BTA2[(4 + h) * HC1 + k] = f2bf(ss - bf2f(sh));
    BTA2[(8 + h) * HC1 + k] = dh;
    BTA2[(12 + h) * HC1 + k] = f2bf(sd - bf2f(dh));
  }
  for (int i = tid; i < 48 * HDIM; i += stride) BTA1[16 * HDIM + i] = 0;
  for (int i = tid; i < 48 * HC1; i += stride) BTA2[16 * HC1 + i] = 0;
}

// ---------------- weight preprocessing: transpose + bf16 ----------------
// BTr[64][1024] (k>=1000 zero), BTp[64][320] (k>=300 zero),
// BT1[512][128] = [W1s|Wl1]^T, BT2[256][256] = [W2s|Wl2]^T, concat biases.
__global__ void convert_weights(const float* __restrict__ W_rna, const float* __restrict__ W_prot,
                                const float* __restrict__ W1s, const float* __restrict__ Wl1,
                                const float* __restrict__ W2s, const float* __restrict__ Wl2,
                                const float* __restrict__ b1, const float* __restrict__ bl1,
                                const float* __restrict__ b2, const float* __restrict__ bl2,
                                ushort* BTr, ushort* BTp, ushort* BT1, ushort* BT2,
                                float* biasL1, float* biasL2) {
  int tid = blockIdx.x * blockDim.x + threadIdx.x;
  int stride = gridDim.x * blockDim.x;
  for (int i = tid; i < 64 * 1024; i += stride) {
    int n = i >> 10, k = i & 1023;
    BTr[i] = (k < D_RNA) ? f2bf(W_rna[k * 64 + n]) : 0;
  }
  for (int i = tid; i < 64 * 320; i += stride) {
    int n = i / 320, k = i - n * 320;
    BTp[i] = (k < D_PROT) ? f2bf(W_prot[k * 64 + n]) : 0;
  }
  for (int i = tid; i < 512 * 128; i += stride) {
    int n = i >> 7, k = i & 127;
    BT1[i] = f2bf(n < 256 ? W1s[k * 256 + n] : Wl1[k * 256 + n - 256]);
  }
  for (int i = tid; i < 256 * 256; i += stride) {
    int n = i >> 8, k = i & 255;
    BT2[i] = f2bf(n < 128 ? W2s[k * 128 + n] : Wl2[k * 128 + n - 128]);
  }
  for (int i = tid; i < 512; i += stride) biasL1[i] = (i < 256) ? b1[i] : bl1[i - 256];
  for (int i = tid; i < 256; i += stride) biasL2[i] = (i < 128) ? b2[i] : bl2[i - 128];
}

#define LDK 72  // padded k-stride (shorts) for 64-wide k tiles: 144B rows -> 2-way-only conflicts

__device__ __forceinline__ f32x4 mfma_bf16(bf16x8 a, bf16x8 b, f32x4 c) {
  return __builtin_amdgcn_mfma_f32_16x16x32_bf16(a, b, c, 0, 0, 0);
}

// ---------------- embedding MFMA GEMM: h0[N,128] bf16 (R5-exact, local optimum) -------
__launch_bounds__(256)
__global__ void embed_gemm(const float* __restrict__ x,
                           const ushort* __restrict__ BTr, const ushort* __restrict__ BTp,
                           const float* __restrict__ b_rna, const float* __restrict__ b_prot,
                           ushort* __restrict__ h0) {
  const bool prot = (blockIdx.x == 1);
  const int Kpad = prot ? 320 : 1024;
  const int acol = prot ? D_RNA : 0;
  const ushort* BT = prot ? BTp : BTr;
  const float* bias = prot ? b_prot : b_rna;
  const int r0 = blockIdx.y * 64;

  __shared__ ushort As[64 * LDK];
  __shared__ ushort Bs[64 * LDK];
  int tid = threadIdx.x;
  int wave = tid >> 6, lane = tid & 63;
  int quad = lane >> 4, lr = lane & 15;
  f32x4 acc[4];
#pragma unroll
  for (int c = 0; c < 4; ++c) acc[c] = (f32x4){0.f, 0.f, 0.f, 0.f};

  int srow = tid >> 2, skq = (tid & 3) * 16;
  const float* aprow = x + (size_t)(r0 + srow) * D_IN;
  const ushort* bprow = BT + (size_t)srow * Kpad;

  float4 fa[4];
  uint4 fb0, fb1;

  auto loadA = [&](int k0) {
#pragma unroll
    for (int q = 0; q < 4; ++q) {
      int kg = acol + k0 + skq + q * 4;
      fa[q] = (kg + 4 <= D_IN) ? *(const float4*)(aprow + kg)
                               : make_float4(0.f, 0.f, 0.f, 0.f);
    }
  };
  auto loadB = [&](int k0) {
    const ushort* bp = bprow + k0 + skq;
    fb0 = *(const uint4*)bp;
    fb1 = *(const uint4*)(bp + 8);
  };

  loadA(0);
  loadB(0);

  for (int k0 = 0; k0 < Kpad; k0 += 64) {
    {
      ushort tmp[16];
#pragma unroll
      for (int q = 0; q < 4; ++q) {
        tmp[q * 4 + 0] = f2bf(fa[q].x); tmp[q * 4 + 1] = f2bf(fa[q].y);
        tmp[q * 4 + 2] = f2bf(fa[q].z); tmp[q * 4 + 3] = f2bf(fa[q].w);
      }
      *(uint4*)&As[srow * LDK + skq] = *(const uint4*)&tmp[0];
      *(uint4*)&As[srow * LDK + skq + 8] = *(const uint4*)&tmp[8];
      *(uint4*)&Bs[srow * LDK + skq] = fb0;
      *(uint4*)&Bs[srow * LDK + skq + 8] = fb1;
    }
    __syncthreads();
    if (k0 + 64 < Kpad) {
      loadA(k0 + 64);
      loadB(k0 + 64);
    }
    int arow = wave * 16 + lr;
    bf16x8 a0 = *(const bf16x8*)&As[arow * LDK + quad * 8];
    bf16x8 a1 = *(const bf16x8*)&As[arow * LDK + 32 + quad * 8];
#pragma unroll
    for (int c = 0; c < 4; ++c) {
      bf16x8 b0 = *(const bf16x8*)&Bs[(c * 16 + lr) * LDK + quad * 8];
      bf16x8 b1 = *(const bf16x8*)&Bs[(c * 16 + lr) * LDK + 32 + quad * 8];
      acc[c] = mfma_bf16(a0, b0, acc[c]);
      acc[c] = mfma_bf16(a1, b1, acc[c]);
    }
    __syncthreads();
  }
  int colb = prot ? 64 : 0;
#pragma unroll
  for (int c = 0; c < 4; ++c) {
#pragma unroll
    for (int j = 0; j < 4; ++j) {
      int row = r0 + wave * 16 + quad * 4 + j;
      int col = c * 16 + lr;
      h0[(size_t)row * HDIM + colb + col] = f2bf(acc[c][j] + bias[col]);
    }
  }
}

// ---------------- layer MFMA GEMM (col-group G=2) + folded attention logits ----------
// grid (ngroups+1, N/64). Regular block x: cols [x*128, x*128+128) = 2 B-tiles sharing
// one staged A-tile. Last x-block uses BTA (single tile) and writes fp32 a_s/a_d:
// out col t(0..3) hi + col t+4 lo summed via shfl_xor(4) -> a_s; cols 8..15 -> a_d.
__launch_bounds__(256)
__global__ void layer_gemm(const ushort* __restrict__ A, int K,
                           const ushort* __restrict__ BT, const float* __restrict__ bias,
                           ushort* __restrict__ out0, ushort* __restrict__ out1, int halfw,
                           const ushort* __restrict__ BTA,
                           float* __restrict__ a_s, float* __restrict__ a_d) {
  const bool att = (blockIdx.x == gridDim.x - 1);
  const int cb = att ? 0 : blockIdx.x * 128;
  const int r0 = blockIdx.y * 64;
  __shared__ ushort As[64 * LDK];
  __shared__ ushort Bs[2][64 * LDK];
  int tid = threadIdx.x;
  int wave = tid >> 6, lane = tid & 63;
  int quad = lane >> 4, lr = lane & 15;
  f32x4 acc[8];
#pragma unroll
  for (int c = 0; c < 8; ++c) acc[c] = (f32x4){0.f, 0.f, 0.f, 0.f};

  int srow = tid >> 2, skq = (tid & 3) * 16;
  const ushort* aprow = A + (size_t)(r0 + srow) * K;
  const ushort* bprow0 = att ? (BTA + (size_t)srow * K)
                             : (BT + (size_t)(cb + srow) * K);
  const ushort* bprow1 = BT + (size_t)(cb + 64 + srow) * K;   // unused when att

  uint4 fa0, fa1, fb00, fb01, fb10, fb11;
  auto loadAB = [&](int k0) {
    const ushort* ap = aprow + k0 + skq;
    fa0 = *(const uint4*)ap;
    fa1 = *(const uint4*)(ap + 8);
    const ushort* bp0 = bprow0 + k0 + skq;
    fb00 = *(const uint4*)bp0;
    fb01 = *(const uint4*)(bp0 + 8);
    if (!att) {
      const ushort* bp1 = bprow1 + k0 + skq;
      fb10 = *(const uint4*)bp1;
      fb11 = *(const uint4*)(bp1 + 8);
    }
  };

  loadAB(0);

  for (int k0 = 0; k0 < K; k0 += 64) {
    *(uint4*)&As[srow * LDK + skq] = fa0;
    *(uint4*)&As[srow * LDK + skq + 8] = fa1;
    *(uint4*)&Bs[0][srow * LDK + skq] = fb00;
    *(uint4*)&Bs[0][srow * LDK + skq + 8] = fb01;
    if (!att) {
      *(uint4*)&Bs[1][srow * LDK + skq] = fb10;
      *(uint4*)&Bs[1][srow * LDK + skq + 8] = fb11;
    }
    __syncthreads();
    if (k0 + 64 < K) loadAB(k0 + 64);
    int arow = wave * 16 + lr;
    bf16x8 a0 = *(const bf16x8*)&As[arow * LDK + quad * 8];
    bf16x8 a1 = *(const bf16x8*)&As[arow * LDK + 32 + quad * 8];
#pragma unroll
    for (int c = 0; c < 4; ++c) {
      bf16x8 b0 = *(const bf16x8*)&Bs[0][(c * 16 + lr) * LDK + quad * 8];
      bf16x8 b1 = *(const bf16x8*)&Bs[0][(c * 16 + lr) * LDK + 32 + quad * 8];
      acc[c] = mfma_bf16(a0, b0, acc[c]);
      acc[c] = mfma_bf16(a1, b1, acc[c]);
    }
    if (!att) {
#pragma unroll
      for (int c = 0; c < 4; ++c) {
        bf16x8 b0 = *(const bf16x8*)&Bs[1][(c * 16 + lr) * LDK + quad * 8];
        bf16x8 b1 = *(const bf16x8*)&Bs[1][(c * 16 + lr) * LDK + 32 + quad * 8];
        acc[4 + c] = mfma_bf16(a0, b0, acc[4 + c]);
        acc[4 + c] = mfma_bf16(a1, b1, acc[4 + c]);
      }
    }
    __syncthreads();
  }
  if (att) {
#pragma unroll
    for (int j = 0; j < 4; ++j) {
      int row = r0 + wave * 16 + quad * 4 + j;
      float v0 = acc[0][j];
      float sum = v0 + __shfl_xor(v0, 4);   // hi + lo partner
      if (lr < 4)                    a_s[(size_t)row * 4 + lr] = sum;
      else if (lr >= 8 && lr < 12)   a_d[(size_t)row * 4 + (lr - 8)] = sum;
    }
    return;
  }
#pragma unroll
  for (int t = 0; t < 2; ++t) {
#pragma unroll
    for (int c = 0; c < 4; ++c) {
#pragma unroll
      for (int j = 0; j < 4; ++j) {
        int row = r0 + wave * 16 + quad * 4 + j;
        int cg = cb + t * 64 + c * 16 + lr;
        ushort v = f2bf(acc[t * 4 + c][j] + bias[cg]);
        if (cg < halfw) out0[(size_t)row * halfw + cg] = v;
        else            out1[(size_t)row * halfw + cg - halfw] = v;
      }
    }
  }
}

// ---------------- fused ONLINE softmax + weighted aggregate + bias + skip (+relu) ----
// Single pass over each node's in-edges: running max m, rescale s/acc on update
// (rare: ~log(deg) times), 2-edge unrolled. VEC=8 lanes (16B uint4 gathers).
// Lane layout: LPH=CH/8 lanes per head, LPN=4*LPH per node, NPW=64/LPN nodes/wave.
__device__ __forceinline__ void load_bf8(const ushort* p, float* o) {
  uint4 q = *(const uint4*)p;
  o[0] = bf2f(q.x & 0xffffu); o[1] = bf2f(q.x >> 16);
  o[2] = bf2f(q.y & 0xffffu); o[3] = bf2f(q.y >> 16);
  o[4] = bf2f(q.z & 0xffffu); o[5] = bf2f(q.z >> 16);
  o[6] = bf2f(q.w & 0xffffu); o[7] = bf2f(q.w >> 16);
}

template <int CH, bool RELU, bool OUT_BF16>
__launch_bounds__(256)
__global__ void gat_fused_kernel(const int* __restrict__ off, const int* __restrict__ srcs,
                                 const float* __restrict__ a_s, const float* __restrict__ a_d,
                                 const ushort* __restrict__ xs,
                                 const float* __restrict__ bias,
                                 const ushort* __restrict__ skip,
                                 void* __restrict__ outv, int N) {
  const int HC  = 4 * CH;
  const int LPH = CH / 8;       // lanes per head
  const int LPN = 4 * LPH;      // lanes per node
  const int NPW = 64 / LPN;     // nodes per wave
  int wave = threadIdx.x >> 6, lane = threadIdx.x & 63;
  int g  = lane / LPN;
  int hl = (lane % LPN) / LPH;
  int li = lane % LPH;
  int n = blockIdx.x * (4 * NPW) + wave * NPW + g;
  if (n >= N) return;
  int i = off[n], end = off[n + 1];
  float adn = a_d[(size_t)n * 4 + hl];
  const int cofs = hl * CH + li * 8;

  float m = -1e30f, s = 0.f;
  float acc[8];
#pragma unroll
  for (int v = 0; v < 8; ++v) acc[v] = 0.f;

  for (; i + 2 <= end; i += 2) {
    int sA = srcs[i], sB = srcs[i + 1];
    float eA = lrelu(a_s[(size_t)sA * 4 + hl] + adn);
    float eB = lrelu(a_s[(size_t)sB * 4 + hl] + adn);
    float xA[8], xB[8];
    load_bf8(xs + (size_t)sA * HC + cofs, xA);
    load_bf8(xs + (size_t)sB * HC + cofs, xB);
    float mn = fmaxf(m, fmaxf(eA, eB));
    if (mn > m) {
      float f = __expf(m - mn);
      s *= f;
#pragma unroll
      for (int v = 0; v < 8; ++v) acc[v] *= f;
      m = mn;
    }
    float pA = __expf(eA - m), pB = __expf(eB - m);
    s += pA + pB;
#pragma unroll
    for (int v = 0; v < 8; ++v) acc[v] += pA * xA[v] + pB * xB[v];
  }
  if (i < end) {
    int sA = srcs[i];
    float eA = lrelu(a_s[(size_t)sA * 4 + hl] + adn);
    float xA[8];
    load_bf8(xs + (size_t)sA * HC + cofs, xA);
    if (eA > m) {
      float f = __expf(m - eA);
      s *= f;
#pragma unroll
      for (int v = 0; v < 8; ++v) acc[v] *= f;
      m = eA;
    }
    float pA = __expf(eA - m);
    s += pA;
#pragma unroll
    for (int v = 0; v < 8; ++v) acc[v] += pA * xA[v];
  }

  float r = s > 0.f ? 1.f / s : 0.f;
  size_t obase = (size_t)n * HC + cofs;
  float sk[8];
  load_bf8(skip + obase, sk);
  float val[8];
#pragma unroll
  for (int v = 0; v < 8; ++v) {
    val[v] = acc[v] * r + bias[cofs + v] + sk[v];
    if (RELU) val[v] = fmaxf(val[v], 0.f);
  }
  if (OUT_BF16) {
    ushort o8[8];
#pragma unroll
    for (int v = 0; v < 8; ++v) o8[v] = f2bf(val[v]);
    *(uint4*)&((ushort*)outv)[obase] = *(const uint4*)o8;
  } else {
    float* op = (float*)outv + obase;
    *(float4*)op = make_float4(val[0], val[1], val[2], val[3]);
    *(float4*)(op + 4) = make_float4(val[4], val[5], val[6], val[7]);
  }
}

// ---------------- host launch ----------------
extern "C" void kernel_launch(void* const* d_in, const int* in_sizes, int n_in,
                              void* d_out, int out_size, void* d_ws, size_t ws_size,
                              hipStream_t stream) {
  const float* x      = (const float*)d_in[0];
  const int*   ei     = (const int*)d_in[1];
  const float* W_rna  = (const float*)d_in[3];
  const float* b_rna  = (const float*)d_in[4];
  const float* W_prot = (const float*)d_in[5];
  const float* b_prot = (const float*)d_in[6];
  const float* W1s    = (const float*)d_in[7];
  const float* W1d    = (const float*)d_in[8];
  const float* at1s   = (const float*)d_in[9];
  const float* at1d   = (const float*)d_in[10];
  const float* bias1  = (const float*)d_in[11];
  const float* Wl1    = (const float*)d_in[12];
  const float* bl1    = (const float*)d_in[13];
  const float* W2s    = (const float*)d_in[14];
  const float* W2d    = (const float*)d_in[15];
  const float* at2s   = (const float*)d_in[16];
  const float* at2d   = (const float*)d_in[17];
  const float* bias2  = (const float*)d_in[18];
  const float* Wl2    = (const float*)d_in[19];
  const float* bl2    = (const float*)d_in[20];

  const int N = in_sizes[0] / D_IN;   // 40000
  const int E = in_sizes[1] / 2;      // 640000
  const int* srcv = ei;
  const int* dstv = ei + E;

  char* ws = (char*)d_ws;
  size_t o = 0;
  auto carve = [&](size_t bytes) {
    void* p = ws + o;
    o += (bytes + 255) & ~(size_t)255;
    return p;
  };
  int* deg    = (int*)carve((size_t)N * 4);
  int* offp   = (int*)carve((size_t)(N + 1) * 4);
  int* cur    = (int*)carve((size_t)N * 4);
  int* srcs   = (int*)carve((size_t)E * 4);
  float* a_s  = (float*)carve((size_t)N * 4 * 4);
  float* a_d  = (float*)carve((size_t)N * 4 * 4);
  ushort* BTr = (ushort*)carve(64 * 1024 * 2);
  ushort* BTp = (ushort*)carve(64 * 320 * 2);
  ushort* BT1 = (ushort*)carve(512 * 128 * 2);
  ushort* BT2 = (ushort*)carve(256 * 256 * 2);
  ushort* BTA1 = (ushort*)carve(64 * 128 * 2);
  ushort* BTA2 = (ushort*)carve(64 * 256 * 2);
  float* biasL1 = (float*)carve(512 * 4);
  float* biasL2 = (float*)carve(256 * 4);
  ushort* h0  = (ushort*)carve((size_t)N * HDIM * 2);
  ushort* xs1 = (ushort*)carve((size_t)N * HC1 * 2);
  ushort* z1  = (ushort*)carve((size_t)N * HC1 * 2);
  ushort* h1  = (ushort*)carve((size_t)N * HC1 * 2);
  ushort* xs2 = h0;   // h0 dead after layer-1 gemm (att folded in)
  ushort* z2  = z1;   // z1 dead after gat_fused1
  float* out = (float*)d_out;

  // 1. counting-sort edges by dst
  zero_i32<<<(N + 255) / 256, 256, 0, stream>>>(deg, N);
  hist_kernel<<<(E + 255) / 256, 256, 0, stream>>>(dstv, deg, E);
  scan_kernel<<<1, 1024, 0, stream>>>(deg, offp, cur, N);
  scatter_kernel<<<(E + 255) / 256, 256, 0, stream>>>(srcv, dstv, cur, srcs, E);
  // 2. fold att (-> BTA tiles) + weight conversion
  fold_att_kernel<<<8, 256, 0, stream>>>(W1s, W1d, at1s, at1d, W2s, W2d, at2s, at2d,
                                         BTA1, BTA2);
  convert_weights<<<256, 256, 0, stream>>>(W_rna, W_prot, W1s, Wl1, W2s, Wl2,
                                           bias1, bl1, bias2, bl2,
                                           BTr, BTp, BT1, BT2, biasL1, biasL2);
  // 3. embedding -> h0[N,128] bf16
  embed_gemm<<<dim3(2, N / 64), 256, 0, stream>>>(x, BTr, BTp, b_rna, b_prot, h0);
  // 4. layer-1: [xs1|z1] = h0 @ [W1s|Wl1] (+bias) and a_s/a_d (att block), bf16
  layer_gemm<<<dim3(5, N / 64), 256, 0, stream>>>(h0, HDIM, BT1, biasL1, xs1, z1, HC1,
                                                  BTA1, a_s, a_d);
  // 5. fused online softmax+aggregate -> h1 = relu(agg + bias1 + z1), bf16
  gat_fused_kernel<CH1, true, true><<<N / 8, 256, 0, stream>>>(offp, srcs, a_s, a_d, xs1,
                                                               bias1, z1, h1, N);
  // 6. layer-2
  layer_gemm<<<dim3(3, N / 64), 256, 0, stream>>>(h1, HC1, BT2, biasL2, xs2, z2, HC2,
                                                  BTA2, a_s, a_d);
  gat_fused_kernel<CH2, false, false><<<N / 16, 256, 0, stream>>>(offp, srcs, a_s, a_d, xs2,
                                                                  bias2, z2, out, N);
}